// Round 5
// baseline (1067.858 us; speedup 1.0000x reference)
//
#include <hip/hip_runtime.h>
#include <cstddef>

typedef __bf16 bf16x8 __attribute__((ext_vector_type(8)));
typedef float  f32x4  __attribute__((ext_vector_type(4)));
typedef float  f32x2  __attribute__((ext_vector_type(2)));
typedef unsigned short u16x8 __attribute__((ext_vector_type(8)));
typedef unsigned short u16x4 __attribute__((ext_vector_type(4)));
typedef unsigned short u16x2 __attribute__((ext_vector_type(2)));

__device__ __forceinline__ float b2f(unsigned short u) {
    union { unsigned int i; float f; } v; v.i = ((unsigned int)u) << 16; return v.f;
}
__device__ __forceinline__ unsigned short f2b(float f) {
    union { float f; unsigned int i; } v; v.f = f;
    unsigned int r = v.i + 0x7fffu + ((v.i >> 16) & 1u);
    return (unsigned short)(r >> 16);
}
__device__ __forceinline__ void gl_lds16(const void* g, void* l) {
    __builtin_amdgcn_global_load_lds((const __attribute__((address_space(1))) void*)g,
                                     (__attribute__((address_space(3))) void*)l,
                                     16, 0, 0);
}

// XCD-aware bijective block swizzle (m204 form).
__device__ __forceinline__ void xcd_swizzle(int& bx, int& by, int& bz) {
    unsigned int nx = gridDim.x, ny = gridDim.y;
    unsigned int n = nx * ny * gridDim.z;
    unsigned int lin = blockIdx.x + nx * (blockIdx.y + ny * blockIdx.z);
    unsigned int q = n >> 3, r = n & 7u;
    unsigned int xcd = lin & 7u, off = lin >> 3;
    unsigned int s = (xcd < r) ? (xcd * (q + 1u) + off)
                               : (r * (q + 1u) + (xcd - r) * q + off);
    bx = (int)(s % nx); s /= nx;
    by = (int)(s % ny);
    bz = (int)(s / ny);
}

// ------------------- input dtype detector -------------------
__global__ __launch_bounds__(64) void detect_kernel(const unsigned short* __restrict__ feat,
                                                    int* __restrict__ flag) {
    __shared__ int cnt;
    if (threadIdx.x == 0) cnt = 0;
    __syncthreads();
    int c = 0;
    for (int i = threadIdx.x; i < 256; i += 64) {
        float v = b2f(feat[i]);
        if (fabsf(v) > 100.0f) ++c;
    }
    atomicAdd(&cnt, c);
    __syncthreads();
    if (threadIdx.x == 0) *flag = (cnt > 16) ? 1 : 0;   // 1 => inputs are fp32
}

// ------------------- zero fill -------------------
__global__ __launch_bounds__(256) void zero_kernel(float* __restrict__ p, int n4) {
    int i = blockIdx.x * 256 + threadIdx.x;
    const f32x4 z = {0.f, 0.f, 0.f, 0.f};
    if (i < n4) ((f32x4*)p)[i] = z;
}

// ------------------- BIG PATH: fused convert(feat->bf16) + global pool -------------------
__global__ __launch_bounds__(256) void convpool_kernel(const void* __restrict__ fq,
                                                       const void* __restrict__ fk,
                                                       unsigned short* __restrict__ FQ,
                                                       unsigned short* __restrict__ FK,
                                                       unsigned short* __restrict__ gq,
                                                       unsigned short* __restrict__ gk,
                                                       const int* __restrict__ flagp) {
    int fl = *flagp;
    int b = blockIdx.y;
    const void* src = blockIdx.z ? fk : fq;
    unsigned short* dst = blockIdx.z ? FK : FQ;
    unsigned short* g   = blockIdx.z ? gk : gq;
    int c0 = blockIdx.x * 512 + threadIdx.x * 2;
    float s0 = 0.f, s1 = 0.f;
    if (fl) {
        const float* sf = (const float*)src;
        #pragma unroll 7
        for (int p = 0; p < 49; ++p) {
            size_t idx = ((size_t)b * 49 + p) * 2048 + c0;
            f32x2 v = *(const f32x2*)(sf + idx);
            u16x2 o; o[0] = f2b(v[0]); o[1] = f2b(v[1]);
            s0 += v[0]; s1 += v[1];
            *(u16x2*)(dst + idx) = o;
        }
    } else {
        const unsigned short* su = (const unsigned short*)src;
        #pragma unroll 7
        for (int p = 0; p < 49; ++p) {
            size_t idx = ((size_t)b * 49 + p) * 2048 + c0;
            u16x2 o = *(const u16x2*)(su + idx);
            s0 += b2f(o[0]); s1 += b2f(o[1]);
            *(u16x2*)(dst + idx) = o;
        }
    }
    u16x2 gm; gm[0] = f2b(s0 * (1.0f / 49.0f)); gm[1] = f2b(s1 * (1.0f / 49.0f));
    *(u16x2*)(g + (size_t)b * 2048 + c0) = gm;
}

// ------------------- SMALL PATH: convert feat -> bf16 -------------------
__global__ __launch_bounds__(256) void convert_kernel(const void* __restrict__ in,
                                                      unsigned short* __restrict__ out,
                                                      const int* __restrict__ flagp) {
    int fl = *flagp;
    size_t i = ((size_t)blockIdx.x * 256 + threadIdx.x) * 8;
    if (fl) {
        const float* inf = (const float*)in;
        f32x4 v0 = *(const f32x4*)(inf + i);
        f32x4 v1 = *(const f32x4*)(inf + i + 4);
        u16x8 o;
        o[0]=f2b(v0[0]); o[1]=f2b(v0[1]); o[2]=f2b(v0[2]); o[3]=f2b(v0[3]);
        o[4]=f2b(v1[0]); o[5]=f2b(v1[1]); o[6]=f2b(v1[2]); o[7]=f2b(v1[3]);
        *(u16x8*)(out + i) = o;
    } else {
        *(u16x8*)(out + i) = *(const u16x8*)((const unsigned short*)in + i);
    }
}

// ------------------- SMALL PATH: global average pool -------------------
__global__ __launch_bounds__(256) void pool_kernel(const void* __restrict__ fq,
                                                   const void* __restrict__ fk,
                                                   unsigned short* __restrict__ gq,
                                                   unsigned short* __restrict__ gk,
                                                   const int* __restrict__ flagp) {
    int fl = *flagp;
    int c = blockIdx.x * 256 + threadIdx.x;
    int b = blockIdx.y;
    const void* src = blockIdx.z ? fk : fq;
    unsigned short* dst = blockIdx.z ? gk : gq;
    size_t base = (size_t)b * 49 * 2048 + c;
    float s = 0.f;
    if (fl) {
        const float* sf = (const float*)src;
        #pragma unroll
        for (int p = 0; p < 49; ++p) s += sf[base + (size_t)p * 2048];
    } else {
        const unsigned short* su = (const unsigned short*)src;
        #pragma unroll
        for (int p = 0; p < 49; ++p) s += b2f(su[base + (size_t)p * 2048]);
    }
    dst[(size_t)b * 2048 + c] = f2b(s * (1.0f / 49.0f));
}

// ------------------- 2-way vectorized transpose+convert (64x64 tiles) -------------------
__global__ __launch_bounds__(256) void transpose2v_kernel(
    const void* __restrict__ s0, const void* __restrict__ s1,
    unsigned short* __restrict__ d0, unsigned short* __restrict__ d1,
    int rows, int cols, const int* __restrict__ flagp) {
    int fl = *flagp;
    int z = blockIdx.z;
    const void* in = z ? s1 : s0;
    unsigned short* out = z ? d1 : d0;
    __shared__ unsigned short tile[64 * 72];
    int bx = blockIdx.x * 64, by = blockIdx.y * 64;
    int tr = threadIdx.x >> 3;
    int tc = (threadIdx.x & 7) * 8;
    #pragma unroll
    for (int h = 0; h < 2; ++h) {
        int r = tr + h * 32;
        if (fl) {
            const float* inf = (const float*)in + (size_t)(by + r) * cols + bx + tc;
            f32x4 v0 = *(const f32x4*)inf;
            f32x4 v1 = *(const f32x4*)(inf + 4);
            u16x8 o;
            o[0]=f2b(v0[0]); o[1]=f2b(v0[1]); o[2]=f2b(v0[2]); o[3]=f2b(v0[3]);
            o[4]=f2b(v1[0]); o[5]=f2b(v1[1]); o[6]=f2b(v1[2]); o[7]=f2b(v1[3]);
            *(u16x8*)(tile + r * 72 + tc) = o;
        } else {
            const unsigned short* inu = (const unsigned short*)in + (size_t)(by + r) * cols + bx + tc;
            *(u16x8*)(tile + r * 72 + tc) = *(const u16x8*)inu;
        }
    }
    __syncthreads();
    #pragma unroll
    for (int h = 0; h < 2; ++h) {
        int oc = tr + h * 32;
        u16x8 v;
        #pragma unroll
        for (int j = 0; j < 8; ++j) v[j] = tile[(tc + j) * 72 + oc];
        *(u16x8*)(out + (size_t)(bx + oc) * rows + by + tc) = v;
    }
}

// ------------------- 4-way vectorized transpose+convert -------------------
__global__ __launch_bounds__(256) void transpose4v_kernel(
    const void* __restrict__ s0, const void* __restrict__ s1,
    const void* __restrict__ s2, const void* __restrict__ s3,
    unsigned short* __restrict__ d0, unsigned short* __restrict__ d1,
    unsigned short* __restrict__ d2, unsigned short* __restrict__ d3,
    int rows, int cols, const int* __restrict__ flagp) {
    int fl = *flagp;
    int z = blockIdx.z;
    const void* in = (z == 0) ? s0 : (z == 1) ? s1 : (z == 2) ? s2 : s3;
    unsigned short* out = (z == 0) ? d0 : (z == 1) ? d1 : (z == 2) ? d2 : d3;
    __shared__ unsigned short tile[64 * 72];
    int bx = blockIdx.x * 64, by = blockIdx.y * 64;
    int tr = threadIdx.x >> 3;
    int tc = (threadIdx.x & 7) * 8;
    #pragma unroll
    for (int h = 0; h < 2; ++h) {
        int r = tr + h * 32;
        if (fl) {
            const float* inf = (const float*)in + (size_t)(by + r) * cols + bx + tc;
            f32x4 v0 = *(const f32x4*)inf;
            f32x4 v1 = *(const f32x4*)(inf + 4);
            u16x8 o;
            o[0]=f2b(v0[0]); o[1]=f2b(v0[1]); o[2]=f2b(v0[2]); o[3]=f2b(v0[3]);
            o[4]=f2b(v1[0]); o[5]=f2b(v1[1]); o[6]=f2b(v1[2]); o[7]=f2b(v1[3]);
            *(u16x8*)(tile + r * 72 + tc) = o;
        } else {
            const unsigned short* inu = (const unsigned short*)in + (size_t)(by + r) * cols + bx + tc;
            *(u16x8*)(tile + r * 72 + tc) = *(const u16x8*)inu;
        }
    }
    __syncthreads();
    #pragma unroll
    for (int h = 0; h < 2; ++h) {
        int oc = tr + h * 32;
        u16x8 v;
        #pragma unroll
        for (int j = 0; j < 8; ++j) v[j] = tile[(tc + j) * 72 + oc];
        *(u16x8*)(out + (size_t)(bx + oc) * rows + by + tc) = v;
    }
}

// ======================= 256x256 8-wave 4-phase/K-tile mega GEMM =======================
// T2(XOR k-swizzle)+T3(phase interleave)+T4(counted waits)+T5(setprio).
// __launch_bounds__(512, 1): R4's (512,2) capped the allocator at 128 VGPRs ->
// acc[8][4] spilled to scratch (WRITE_SIZE 1.27 GB, MfmaUtil 6.8%). LDS=128KB
// already pins occupancy at 1 block/CU (8 waves), so the cap bought nothing.
__global__ __launch_bounds__(512, 1) void mega256_kernel(
    const unsigned short* __restrict__ FQ, const unsigned short* __restrict__ FK,
    const unsigned short* __restrict__ gq, const unsigned short* __restrict__ gk,
    const unsigned short* __restrict__ WD1T, const unsigned short* __restrict__ MWD1T,
    const unsigned short* __restrict__ WG1T, const unsigned short* __restrict__ MWG1T,
    const unsigned short* __restrict__ W2dq, const unsigned short* __restrict__ W2dk,
    const unsigned short* __restrict__ W2gq, const unsigned short* __restrict__ W2gk,
    const void* __restrict__ bd1, const void* __restrict__ mbd1,
    const void* __restrict__ bg1, const void* __restrict__ mbg1,
    float* __restrict__ rawdq, float* __restrict__ rawdk,
    float* __restrict__ rawgq, float* __restrict__ rawgk,
    const int* __restrict__ flagp)
{
    int fl = *flagp;
    int bx, by, bz;
    xcd_swizzle(bx, by, bz);
    int z = bz;
    const unsigned short *A, *Bt, *W2; const void* b1; float* outp;
    size_t m0;
    if (by < 25) {
        // dense: by<24 full 256 tiles; by==24 tail of 128 rows (6272 = 24*256+128)
        A = z ? FK : FQ;  Bt = z ? MWD1T : WD1T;  W2 = z ? W2dk : W2dq;
        b1 = z ? mbd1 : bd1;  outp = z ? rawdk : rawdq;
        m0 = (size_t)by * 256;
    } else {
        // global head: 128 rows
        A = z ? gk : gq;  Bt = z ? MWG1T : WG1T;  W2 = z ? W2gk : W2gq;
        b1 = z ? mbg1 : bg1;  outp = z ? rawgk : rawgq;
        m0 = 0;
    }
    int mloc = (by >= 24) ? 128 : 256;     // valid local rows (others clamped+discarded)
    size_t n0 = (size_t)bx * 256;

    const int K = 2048;
    __shared__ unsigned short smem[65536];   // 128 KB
    unsigned short* As0v = smem;
    unsigned short* Bs0v = smem + 16384;
    unsigned short* As1v = smem + 32768;
    unsigned short* Bs1v = smem + 49152;
    unsigned short* Hs   = smem;             // phase2: 256 x 72 (aliases bufs, used after K-loop)

    int tid  = threadIdx.x;
    int lane = tid & 63;
    int w    = tid >> 6;                     // 0..7
    int wm = w & 1, wn = w >> 1;             // 2M x 4N wave grid
    int quad = lane >> 4, l16 = lane & 15;
    int lrow = lane >> 3;
    int kc   = (lane & 7) ^ lrow;            // pre-swizzled global k-slot (rule 21)
    int swz  = l16 & 7;

    const unsigned short* gA[4];
    const unsigned short* gB[4];
    int offAB[4];
    #pragma unroll
    for (int c = 0; c < 4; ++c) {
        int ra = (w * 32 + c * 8 + lrow) & (mloc - 1);   // clamp for 128-row tiles
        int rb = w * 32 + c * 8 + lrow;
        gA[c] = A  + (m0 + ra) * (size_t)K + kc * 8;
        gB[c] = Bt + (n0 + rb) * (size_t)K + kc * 8;
        offAB[c] = w * 2048 + c * 512;
    }

    const f32x4 zero4 = {0.f, 0.f, 0.f, 0.f};
    f32x4 acc[8][4];
    #pragma unroll
    for (int i = 0; i < 8; ++i)
        #pragma unroll
        for (int j = 0; j < 4; ++j) acc[i][j] = zero4;
    bf16x8 bfr[4][2];
    bf16x8 af[2][2];

#define STG_A(c, Dst) do { gl_lds16(gA[(c)], (Dst) + offAB[(c)]); gA[(c)] += 64; } while (0)
#define STG_B(c, Dst) do { gl_lds16(gB[(c)], (Dst) + offAB[(c)]); gB[(c)] += 64; } while (0)

#define PH(Acur, Bcur, q, STAGES) do {                                          \
    if ((q) == 0) {                                                             \
        _Pragma("unroll")                                                       \
        for (int nt_ = 0; nt_ < 4; ++nt_) {                                     \
            _Pragma("unroll")                                                   \
            for (int ki_ = 0; ki_ < 2; ++ki_) {                                 \
                int sc_ = (((ki_ * 4) + quad) ^ swz) << 3;                      \
                bfr[nt_][ki_] = *(const bf16x8*)((Bcur) + (wn * 64 + nt_ * 16 + l16) * 64 + sc_); \
            }                                                                   \
        }                                                                       \
    }                                                                           \
    _Pragma("unroll")                                                           \
    for (int i_ = 0; i_ < 2; ++i_) {                                            \
        _Pragma("unroll")                                                       \
        for (int ki_ = 0; ki_ < 2; ++ki_) {                                     \
            int sc_ = (((ki_ * 4) + quad) ^ swz) << 3;                          \
            af[i_][ki_] = *(const bf16x8*)((Acur) + (wm * 128 + (2 * (q) + i_) * 16 + l16) * 64 + sc_); \
        }                                                                       \
    }                                                                           \
    STAGES                                                                      \
    __builtin_amdgcn_s_barrier();                                               \
    asm volatile("s_waitcnt lgkmcnt(0)" ::: "memory");                          \
    __builtin_amdgcn_sched_barrier(0);                                          \
    __builtin_amdgcn_s_setprio(1);                                              \
    _Pragma("unroll")                                                           \
    for (int i_ = 0; i_ < 2; ++i_)                                              \
        _Pragma("unroll")                                                       \
        for (int nt_ = 0; nt_ < 4; ++nt_)                                       \
            _Pragma("unroll")                                                   \
            for (int ki_ = 0; ki_ < 2; ++ki_)                                   \
                acc[2 * (q) + i_][nt_] = __builtin_amdgcn_mfma_f32_16x16x32_bf16(af[i_][ki_], bfr[nt_][ki_], acc[2 * (q) + i_][nt_], 0, 0, 0); \
    __builtin_amdgcn_s_setprio(0);                                              \
    __builtin_amdgcn_s_barrier();                                               \
} while (0)

    // prologue: stage K-tile 0 into buf0 (8 loads/thread in flight)
    STG_A(0, As0v); STG_A(1, As0v); STG_A(2, As0v); STG_A(3, As0v);
    STG_B(0, Bs0v); STG_B(1, Bs0v); STG_B(2, Bs0v); STG_B(3, Bs0v);

    #pragma unroll 1
    for (int tt = 0; tt < 16; ++tt) {
        // ---- even tile: compute buf0, stage t+1 -> buf1 ----
        asm volatile("s_waitcnt vmcnt(0)" ::: "memory");
        __builtin_amdgcn_s_barrier();
        PH(As0v, Bs0v, 0, { STG_A(0, As1v); STG_A(1, As1v); STG_B(0, Bs1v); });
        PH(As0v, Bs0v, 1, { STG_A(2, As1v); STG_A(3, As1v); STG_B(1, Bs1v); });
        PH(As0v, Bs0v, 2, { STG_B(2, Bs1v); STG_B(3, Bs1v); });
        PH(As0v, Bs0v, 3, {});
        // ---- odd tile: compute buf1, stage t+1 -> buf0 (none on last) ----
        asm volatile("s_waitcnt vmcnt(0)" ::: "memory");
        __builtin_amdgcn_s_barrier();
        if (tt < 15) {
            PH(As1v, Bs1v, 0, { STG_A(0, As0v); STG_A(1, As0v); STG_B(0, Bs0v); });
            PH(As1v, Bs1v, 1, { STG_A(2, As0v); STG_A(3, As0v); STG_B(1, Bs0v); });
            PH(As1v, Bs1v, 2, { STG_B(2, Bs0v); STG_B(3, Bs0v); });
            PH(As1v, Bs1v, 3, {});
        } else {
            PH(As1v, Bs1v, 0, {});
            PH(As1v, Bs1v, 1, {});
            PH(As1v, Bs1v, 2, {});
            PH(As1v, Bs1v, 3, {});
        }
    }
#undef PH
#undef STG_A
#undef STG_B

    // ---------------- phase 2: relu(raw1+b1) @ W2T ----------------
    float b1v[4];
    #pragma unroll
    for (int nt = 0; nt < 4; ++nt) {
        int col = (int)n0 + wn * 64 + nt * 16 + l16;
        b1v[nt] = fl ? ((const float*)b1)[col] : b2f(((const unsigned short*)b1)[col]);
    }
    // pack H into bf16 now: frees the 128 acc VGPRs before the chunk loop
    u16x4 hbf[8][4];
    #pragma unroll
    for (int mt = 0; mt < 8; ++mt)
        #pragma unroll
        for (int nt = 0; nt < 4; ++nt)
            #pragma unroll
            for (int r = 0; r < 4; ++r)
                hbf[mt][nt][r] = f2b(fmaxf(acc[mt][nt][r] + b1v[nt], 0.f));

    int wm2 = w >> 1, wn2 = w & 1;           // 4M x 2N retile for GEMM2
    f32x4 acc2[4][4];
    #pragma unroll
    for (int i = 0; i < 4; ++i)
        #pragma unroll
        for (int j = 0; j < 4; ++j) acc2[i][j] = zero4;

    const unsigned short* W2g = W2;          // W2T: 128 x 2048
    #pragma unroll
    for (int j = 0; j < 4; ++j) {
        if (wn == j) {   // this wave's 64 hidden cols become the K-chunk
            #pragma unroll
            for (int mt = 0; mt < 8; ++mt)
                #pragma unroll
                for (int nt = 0; nt < 4; ++nt)
                    #pragma unroll
                    for (int r = 0; r < 4; ++r)
                        Hs[(wm * 128 + mt * 16 + quad * 4 + r) * 72 + nt * 16 + l16] = hbf[mt][nt][r];
        }
        asm volatile("s_waitcnt lgkmcnt(0)" ::: "memory");
        __builtin_amdgcn_s_barrier();
        #pragma unroll
        for (int ki = 0; ki < 2; ++ki) {
            bf16x8 ha[4], wb[4];
            #pragma unroll
            for (int mt = 0; mt < 4; ++mt)
                ha[mt] = *(const bf16x8*)(Hs + (wm2 * 64 + mt * 16 + l16) * 72 + ki * 32 + quad * 8);
            #pragma unroll
            for (int et = 0; et < 4; ++et)
                wb[et] = *(const bf16x8*)(W2g + (size_t)(wn2 * 64 + et * 16 + l16) * 2048
                                          + n0 + j * 64 + ki * 32 + quad * 8);
            #pragma unroll
            for (int mt = 0; mt < 4; ++mt)
                #pragma unroll
                for (int et = 0; et < 4; ++et)
                    acc2[mt][et] = __builtin_amdgcn_mfma_f32_16x16x32_bf16(ha[mt], wb[et], acc2[mt][et], 0, 0, 0);
        }
        asm volatile("s_waitcnt lgkmcnt(0)" ::: "memory");
        __builtin_amdgcn_s_barrier();        // WAR before next chunk's H overwrite
    }

    #pragma unroll
    for (int et = 0; et < 4; ++et) {
        int col = wn2 * 64 + et * 16 + l16;
        #pragma unroll
        for (int mt = 0; mt < 4; ++mt)
            #pragma unroll
            for (int r = 0; r < 4; ++r) {
                int rl = wm2 * 64 + mt * 16 + quad * 4 + r;
                if (rl < mloc)
                    atomicAdd(&outp[(m0 + rl) * 128 + col], acc2[mt][et][r]);
            }
    }
}

// ======================= MLP core (small path, unchanged) =======================
__device__ __forceinline__ void mlp_body(
    const unsigned short* __restrict__ A, const unsigned short* __restrict__ Bt,
    const unsigned short* __restrict__ W2, const void* __restrict__ b1,
    float* __restrict__ outp, size_t m0, size_t n0, int fl)
{
    const int K = 2048;
    __shared__ unsigned short smem[32768];   // 64 KB
    unsigned short* As0 = smem;
    unsigned short* Bs0 = smem + 8192;
    unsigned short* As1 = smem + 16384;
    unsigned short* Bs1 = smem + 24576;
    unsigned short* W2s = smem;
    unsigned short* Hs  = smem + 8192;

    int tid  = threadIdx.x;
    int lane = tid & 63;
    int w    = tid >> 6;
    int wm = w & 1, wn = w >> 1;
    int quad = lane >> 4, l16 = lane & 15;
    int lrow = lane >> 3;
    int kc   = (lane & 7) ^ lrow;

    const unsigned short* gA[4];
    const unsigned short* gB[4];
    int off[4];
    #pragma unroll
    for (int c = 0; c < 4; ++c) {
        int row = w * 32 + c * 8 + lrow;
        gA[c] = A  + (m0 + row) * (size_t)K + kc * 8;
        gB[c] = Bt + (n0 + row) * (size_t)K + kc * 8;
        off[c] = w * 2048 + c * 512;
    }

    const f32x4 zero4 = {0.f, 0.f, 0.f, 0.f};
    f32x4 acc[4][4];
    #pragma unroll
    for (int i = 0; i < 4; ++i)
        #pragma unroll
        for (int j = 0; j < 4; ++j) acc[i][j] = zero4;

    int swz = l16 & 7;

#define STAGE(Ad, Bd) do { \
    _Pragma("unroll") \
    for (int c = 0; c < 4; ++c) { gl_lds16(gA[c], (Ad) + off[c]); gA[c] += 64; } \
    _Pragma("unroll") \
    for (int c = 0; c < 4; ++c) { gl_lds16(gB[c], (Bd) + off[c]); gB[c] += 64; } \
} while (0)

#define CSTEP(Asrc, Bsrc) do { \
    _Pragma("unroll") \
    for (int k0 = 0; k0 < 64; k0 += 32) { \
        bf16x8 af[4], bfr[4]; \
        _Pragma("unroll") \
        for (int mt = 0; mt < 4; ++mt) { \
            int row = wm * 64 + mt * 16 + l16; \
            int sc  = (((k0 >> 3) + quad) ^ swz) << 3; \
            af[mt] = *(const bf16x8*)((Asrc) + row * 64 + sc); \
        } \
        _Pragma("unroll") \
        for (int nt = 0; nt < 4; ++nt) { \
            int row = wn * 64 + nt * 16 + l16; \
            int sc  = (((k0 >> 3) + quad) ^ swz) << 3; \
            bfr[nt] = *(const bf16x8*)((Bsrc) + row * 64 + sc); \
        } \
        __builtin_amdgcn_s_setprio(1); \
        _Pragma("unroll") \
        for (int mt = 0; mt < 4; ++mt) \
            _Pragma("unroll") \
            for (int nt = 0; nt < 4; ++nt) \
                acc[mt][nt] = __builtin_amdgcn_mfma_f32_16x16x32_bf16(af[mt], bfr[nt], acc[mt][nt], 0, 0, 0); \
        __builtin_amdgcn_s_setprio(0); \
    } \
} while (0)

    STAGE(As0, Bs0);
    #pragma unroll 1
    for (int kb2 = 0; kb2 < 16; ++kb2) {
        STAGE(As1, Bs1);
        asm volatile("s_waitcnt vmcnt(8)" ::: "memory");
        __builtin_amdgcn_s_barrier();
        __builtin_amdgcn_sched_barrier(0);
        CSTEP(As0, Bs0);
        asm volatile("s_waitcnt lgkmcnt(0)" ::: "memory");
        __builtin_amdgcn_sched_barrier(0);
        __builtin_amdgcn_s_barrier();
        if (kb2 < 15) {
            STAGE(As0, Bs0);
            asm volatile("s_waitcnt vmcnt(8)" ::: "memory");
        } else {
            asm volatile("s_waitcnt vmcnt(0)" ::: "memory");
        }
        __builtin_amdgcn_s_barrier();
        __builtin_amdgcn_sched_barrier(0);
        CSTEP(As1, Bs1);
        asm volatile("s_waitcnt lgkmcnt(0)" ::: "memory");
        __builtin_amdgcn_sched_barrier(0);
        __builtin_amdgcn_s_barrier();
    }
#undef STAGE
#undef CSTEP

    float b1v[4];
    #pragma unroll
    for (int nt = 0; nt < 4; ++nt) {
        int col = (int)n0 + wn * 64 + nt * 16 + l16;
        b1v[nt] = fl ? ((const float*)b1)[col] : b2f(((const unsigned short*)b1)[col]);
    }

    f32x4 acc2[4][4];
    #pragma unroll
    for (int i = 0; i < 4; ++i)
        #pragma unroll
        for (int j = 0; j < 4; ++j) acc2[i][j] = zero4;

    #pragma unroll
    for (int hf = 0; hf < 2; ++hf) {
        __syncthreads();
        if (wn == hf) {
            #pragma unroll
            for (int mt = 0; mt < 4; ++mt)
                #pragma unroll
                for (int nt = 0; nt < 4; ++nt)
                    #pragma unroll
                    for (int r = 0; r < 4; ++r) {
                        float v = fmaxf(acc[mt][nt][r] + b1v[nt], 0.f);
                        Hs[(wm * 64 + mt * 16 + quad * 4 + r) * 72 + nt * 16 + l16] = f2b(v);
                    }
        } else {
            #pragma unroll
            for (int c = 0; c < 8; ++c) {
                const unsigned short* g = W2 + (size_t)(wm * 64 + c * 8 + lrow) * 2048
                                          + n0 + hf * 64 + kc * 8;
                gl_lds16(g, W2s + wm * 4096 + c * 512);
            }
        }
        __syncthreads();
        #pragma unroll
        for (int k0 = 0; k0 < 64; k0 += 32) {
            bf16x8 ha[4], wb[4];
            #pragma unroll
            for (int mt = 0; mt < 4; ++mt)
                ha[mt] = *(const bf16x8*)(Hs + (wm * 64 + mt * 16 + l16) * 72 + k0 + quad * 8);
            #pragma unroll
            for (int et = 0; et < 4; ++et) {
                int row = wn * 64 + et * 16 + l16;
                int sc  = (((k0 >> 3) + quad) ^ swz) << 3;
                wb[et] = *(const bf16x8*)(W2s + row * 64 + sc);
            }
            #pragma unroll
            for (int mt = 0; mt < 4; ++mt)
                #pragma unroll
                for (int et = 0; et < 4; ++et)
                    acc2[mt][et] = __builtin_amdgcn_mfma_f32_16x16x32_bf16(ha[mt], wb[et], acc2[mt][et], 0, 0, 0);
        }
    }

    #pragma unroll
    for (int et = 0; et < 4; ++et) {
        int col = wn * 64 + et * 16 + l16;
        #pragma unroll
        for (int mt = 0; mt < 4; ++mt)
            #pragma unroll
            for (int r = 0; r < 4; ++r) {
                size_t row = m0 + wm * 64 + mt * 16 + quad * 4 + r;
                atomicAdd(&outp[row * 128 + col], acc2[mt][et][r]);
            }
    }
}

// ---- SMALL PATH: pair mlp (z selects pointer pair) ----
__global__ __launch_bounds__(256) void mlp_kernel(
    const unsigned short* __restrict__ A0, const unsigned short* __restrict__ A1,
    const unsigned short* __restrict__ Bt0, const unsigned short* __restrict__ Bt1,
    const unsigned short* __restrict__ W20, const unsigned short* __restrict__ W21,
    const void* __restrict__ b10, const void* __restrict__ b11,
    float* __restrict__ out0, float* __restrict__ out1,
    const int* __restrict__ flagp)
{
    int fl = *flagp;
    int bx, by, bz;
    xcd_swizzle(bx, by, bz);
    int z  = bz;
    mlp_body(z ? A1 : A0, z ? Bt1 : Bt0, z ? W21 : W20, z ? b11 : b10,
             z ? out1 : out0, (size_t)by * 128, (size_t)bx * 128, fl);
}

// ---- fused dense: bias + l2norm (writes qd/kd) + sim 49x49 + argmax + matched + pos ----
__global__ __launch_bounds__(256) void simmatch_kernel(
    const float* __restrict__ rawdq, const float* __restrict__ rawdk,
    const void* __restrict__ bd2, const void* __restrict__ mbd2,
    unsigned short* __restrict__ qd, unsigned short* __restrict__ kd,
    unsigned short* __restrict__ matched, float* __restrict__ pos,
    const int* __restrict__ flagp) {
    int fl = *flagp;
    __shared__ float f1s[49 * 128];
    __shared__ float f2s[49 * 128];
    int b = blockIdx.x;
    int half = blockIdx.y;
    int t = threadIdx.x;
    size_t base = (size_t)b * 49 * 128;

    int rr = t >> 2, jq = t & 3;
    if (rr < 49) {
        #pragma unroll
        for (int br = 0; br < 2; ++br) {
            const float* raw = br ? rawdk : rawdq;
            const void* bias = br ? mbd2 : bd2;
            unsigned short* outg = br ? kd : qd;
            float* fs = br ? f2s : f1s;
            size_t idx = base + (size_t)rr * 128 + jq * 32;
            float x[32];
            float ss = 0.f;
            #pragma unroll
            for (int c = 0; c < 32; ++c) {
                float bv = fl ? ((const float*)bias)[jq * 32 + c]
                              : b2f(((const unsigned short*)bias)[jq * 32 + c]);
                x[c] = raw[idx + c] + bv;
                ss += x[c] * x[c];
            }
            ss += __shfl_xor(ss, 1); ss += __shfl_xor(ss, 2);
            float rs = rsqrtf(fmaxf(ss, 1e-12f));
            #pragma unroll
            for (int c = 0; c < 32; ++c) {
                unsigned short us = f2b(x[c] * rs);
                if (half == 0) outg[idx + c] = us;
                fs[rr * 128 + jq * 32 + c] = b2f(us);
            }
        }
    }
    __syncthreads();

    int i0 = t >> 2, q4 = t & 3;
    int i = half * 25 + i0;
    int ilim = half ? 24 : 25;
    if (i0 < ilim) {
        int mlo = q4 * 13;
        int mhi = mlo + 13; if (mhi > 49) mhi = 49;
        float best = -1e30f; int bi = 1 << 20;
        const f32x4* va = (const f32x4*)(f1s + i * 128);
        for (int m = mlo; m < mhi; ++m) {
            const f32x4* vb = (const f32x4*)(f2s + m * 128);
            float d = 0.f;
            #pragma unroll
            for (int j = 0; j < 32; ++j) {
                f32x4 a = va[j], bb = vb[j];
                d += a[0]*bb[0] + a[1]*bb[1] + a[2]*bb[2] + a[3]*bb[3];
            }
            if (d > best) { best = d; bi = m; }
        }
        #pragma unroll
        for (int off = 1; off < 4; off <<= 1) {
            float ov = __shfl_xor(best, off);
            int   oi = __shfl_xor(bi, off);
            if (ov > best || (ov == best && oi < bi)) { best = ov; bi = oi; }
        }
        if (q4 == 0) pos[b * 49 + i] = best * 5.0f;
        for (int j = q4 * 32; j < q4 * 32 + 32; ++j)
            matched[base + (size_t)i * 128 + j] = f2b(f2s[bi * 128 + j]);
    }
}

// ------------------- fused dense InfoNCE sum-of-exp, col-split x14 -------------------
#define KS 136
#define NZSPLIT 14
__global__ __launch_bounds__(256) void lse_kernel(const unsigned short* __restrict__ qd,
                                                  const unsigned short* __restrict__ matched,
                                                  float* __restrict__ lsep) {
    __shared__ unsigned short As[128 * KS];
    __shared__ unsigned short Bs[64 * KS];
    __shared__ float rsum[128];
    int tid  = threadIdx.x;
    int lane = tid & 63, wave = tid >> 6;
    int wm = wave & 1, wn = wave >> 1;
    int quad = lane >> 4, l16 = lane & 15;
    size_t m0 = (size_t)blockIdx.x * 128;
    int z = blockIdx.y;

    #pragma unroll
    for (int i = 0; i < 8; ++i) {
        int l = tid + 256 * i;
        int row = l >> 4, ko = (l & 15) << 3;
        u16x8 v = *(const u16x8*)(qd + (m0 + row) * 128 + ko);
        *(u16x8*)(As + row * KS + ko) = v;
    }
    if (tid < 128) rsum[tid] = 0.f;

    float rs[4][4];
    #pragma unroll
    for (int mt = 0; mt < 4; ++mt)
        #pragma unroll
        for (int r = 0; r < 4; ++r) rs[mt][r] = 0.f;

    const f32x4 zero4 = {0.f, 0.f, 0.f, 0.f};
    int nlo = z * 448, nhi = nlo + 448;
    for (int n0 = nlo; n0 < nhi; n0 += 64) {
        __syncthreads();
        #pragma unroll
        for (int i = 0; i < 4; ++i) {
            int l = tid + 256 * i;
            int row = l >> 4, ko = (l & 15) << 3;
            u16x8 v = *(const u16x8*)(matched + (size_t)(n0 + row) * 128 + ko);
            *(u16x8*)(Bs + row * KS + ko) = v;
        }
        __syncthreads();
        f32x4 acc[4][2];
        #pragma unroll
        for (int mt = 0; mt < 4; ++mt) { acc[mt][0] = zero4; acc[mt][1] = zero4; }
        #pragma unroll
        for (int k0 = 0; k0 < 128; k0 += 32) {
            bf16x8 af[4], bfr[2];
            #pragma unroll
            for (int mt = 0; mt < 4; ++mt)
                af[mt] = *(const bf16x8*)(As + (wm * 64 + mt * 16 + l16) * KS + k0 + quad * 8);
            #pragma unroll
            for (int nt = 0; nt < 2; ++nt)
                bfr[nt] = *(const bf16x8*)(Bs + (wn * 32 + nt * 16 + l16) * KS + k0 + quad * 8);
            #pragma unroll
            for (int mt = 0; mt < 4; ++mt)
                #pragma unroll
                for (int nt = 0; nt < 2; ++nt)
                    acc[mt][nt] = __builtin_amdgcn_mfma_f32_16x16x32_bf16(af[mt], bfr[nt], acc[mt][nt], 0, 0, 0);
        }
        #pragma unroll
        for (int mt = 0; mt < 4; ++mt)
            #pragma unroll
            for (int r = 0; r < 4; ++r)
                rs[mt][r] += __expf(acc[mt][0][r] * 5.0f) + __expf(acc[mt][1][r] * 5.0f);
    }
    #pragma unroll
    for (int mt = 0; mt < 4; ++mt)
        #pragma unroll
        for (int r = 0; r < 4; ++r) {
            float v = rs[mt][r];
            v += __shfl_xor(v, 1); v += __shfl_xor(v, 2);
            v += __shfl_xor(v, 4); v += __shfl_xor(v, 8);
            if (l16 == 0) atomicAdd(&rsum[wm * 64 + mt * 16 + quad * 4 + r], v);
        }
    __syncthreads();
    if (tid < 128) lsep[(size_t)z * 6272 + m0 + tid] = rsum[tid];
}

// ---- fused global: bias + l2norm (on the fly) + InfoNCE row term ----
__global__ __launch_bounds__(128) void lg_kernel(const float* __restrict__ rawgq,
                                                 const float* __restrict__ rawgk,
                                                 const void* __restrict__ bg2,
                                                 const void* __restrict__ mbg2,
                                                 float* __restrict__ lgrow,
                                                 const int* __restrict__ flagp) {
    int fl = *flagp;
    __shared__ float ksf[128 * 128];
    __shared__ float qsf[8 * 128];
    int t = threadIdx.x;
    int rbase = blockIdx.x * 8;
    {
        const float* rk = rawgk + (size_t)t * 128;
        float ss = 0.f;
        for (int c = 0; c < 128; ++c) {
            float bv = fl ? ((const float*)mbg2)[c] : b2f(((const unsigned short*)mbg2)[c]);
            float xx = rk[c] + bv;
            ss += xx * xx;
        }
        float rsv = rsqrtf(fmaxf(ss, 1e-12f));
        for (int c = 0; c < 128; ++c) {
            float bv = fl ? ((const float*)mbg2)[c] : b2f(((const unsigned short*)mbg2)[c]);
            ksf[t * 128 + c] = b2f(f2b((rk[c] + bv) * rsv));
        }
    }
    if (t < 8) {
        const float* rq = rawgq + (size_t)(rbase + t) * 128;
        float ss = 0.f;
        for (int c = 0; c < 128; ++c) {
            float bv = fl ? ((const float*)bg2)[c] : b2f(((const unsigned short*)bg2)[c]);
            float xx = rq[c] + bv;
            ss += xx * xx;
        }
        float rsv = rsqrtf(fmaxf(ss, 1e-12f));
        for (int c = 0; c < 128; ++c) {
            float bv = fl ? ((const float*)bg2)[c] : b2f(((const unsigned short*)bg2)[c]);
            qsf[t * 128 + c] = b2f(f2b((rq[c] + bv) * rsv));
        }
    }
    __syncthreads();
    int rl = t >> 4, jg = t & 15;
    int row = rbase + rl;
    float se = 0.f, diag = 0.f;
    for (int jj = 0; jj < 8; ++jj) {
        int j = jg * 8 + jj;
        float d = 0.f;
        #pragma unroll 8
        for (int c = 0; c < 128; ++c) d += qsf[rl * 128 + c] * ksf[j * 128 + c];
        d *= 5.0f;
        se += __expf(d);
        if (j == row) diag = d;
    }
    #pragma unroll
    for (int off = 1; off < 16; off <<= 1) { se += __shfl_xor(se, off); diag += __shfl_xor(diag, off); }
    if (jg == 0) lgrow[row] = logf(se) - diag;
}

// ------------------- final combine, dtype-hedged output -------------------
__global__ __launch_bounds__(256) void final_kernel(const float* __restrict__ lsep,
                                                    const float* __restrict__ pos,
                                                    const float* __restrict__ lgrow,
                                                    unsigned int* __restrict__ out) {
    int t = threadIdx.x;
    float s = 0.f;
    for (int i = t; i < 6272; i += 256) {
        float se = 0.f;
        #pragma unroll
        for (int zz = 0; zz < NZSPLIT; ++zz) se += lsep[zz * 6272 + i];
        s += logf(se) - pos[i];
    }
    float g = (t < 128) ? lgrow[t] : 0.f;
    #pragma unroll
    for (int off = 32; off >= 1; off >>= 1) { s += __shfl_xor(s, off); g += __shfl_xor(g, off); }
    __shared__ float p8[8];
    if ((t & 63) == 0) { p8[t >> 6] = s; p8[4 + (t >> 6)] = g; }
    __syncthreads();
    if (t == 0) {
        float ld  = (p8[0] + p8[1] + p8[2] + p8[3]) * (1.0f / 6272.0f);
        float lg  = (p8[4] + p8[5] + p8[6] + p8[7]) * (1.0f / 128.0f);
        float total = 0.5f * lg + 0.5f * ld;
        unsigned int L = f2b(total);
        union { float f; unsigned int u; } tb; tb.f = total;
        unsigned int base = (tb.u & 0xFFFF0000u) | L;
        unsigned int bu = base; float be = 1e30f;
        #pragma unroll
        for (int d = -1; d <= 1; ++d) {
            unsigned int c = base + ((unsigned int)d << 16);
            union { unsigned int u; float f; } cv; cv.u = c;
            float e = fabsf(cv.f - total);
            if (e < be) { be = e; bu = c; }
        }
        out[0] = bu;
    }
}

// ------------------- BIG layout (needs 99,652,608 B) -------------------
#define A_FQ     ((size_t)0)
#define A_FK     ((size_t)25690112)
#define A_WD1T   ((size_t)51380224)
#define A_MWD1T  ((size_t)59768832)
#define A_WG1T   ((size_t)68157440)
#define A_MWG1T  ((size_t)76546048)
#define A_W2DQ   ((size_t)84934656)
#define A_W2DK   ((size_t)85458944)
#define A_W2GQ   ((size_t)85983232)
#define A_W2GK   ((size_t)86507520)
#define A_RAWDQ  ((size_t)87031808)
#define A_RAWDK  ((size_t)90243072)
#define A_RAWGQ  ((size_t)93454336)
#define A_RAWGK  ((size_t)93519872)
#define A_GQ     ((size_t)93585408)
#define A_GK     ((size_t)94109696)
#define A_QD     ((size_t)94633984)
#define A_KD     ((size_t)96239616)
#define A_MT     ((size_t)97845248)
#define A_POS    ((size_t)99450880)
#define A_LSEP   ((size_t)99475968)
#define A_LGR    ((size_t)99651584)
#define A_FLAG   ((size_t)99652096)
#define A_NEED   ((size_t)99652608)
// lsep (14 x 6272 f32 = 343 KB) lives in the rawdq region (dead after simmatch).

// ------------------- SMALL layout (peak 43.78 MB) -------------------
#define B_SLOTA  ((size_t)0)
#define B_QD     ((size_t)0)
#define B_KD     ((size_t)1605632)
#define B_MT     ((size_t)3211264)
#define B_SLOTB  ((size_t)8388608)
#define B_W2DQ   ((size_t)34078720)
#define B_W2DK   ((size_t)34603008)
#define B_W2GQ   ((size_t)35127296)
#define B_W2GK   ((size_t)35651584)
#define B_RAWDQ  ((size_t)36175872)
#define B_RAWDK  ((size_t)39387136)
#define B_RAWGQ  ((size_t)42598400)
#define B_RAWGK  ((size_t)42663936)
#define B_GQ     ((size_t)42729472)
#define B_GK     ((size_t)43253760)
#define B_POS    ((size_t)42729472)
#define B_LSEP   ((size_t)42754560)
#define B_LGR    ((size_t)42930176)
#define B_FLAG   ((size_t)42930688)

extern "C" void kernel_launch(void* const* d_in, const int* in_sizes, int n_in,
                              void* d_out, int out_size, void* d_ws, size_t ws_size,
                              hipStream_t stream) {
    (void)in_sizes; (void)n_in; (void)out_size;
    const void* feat_q = d_in[0];
    const void* feat_k = d_in[1];
    const void* Wg1 = d_in[2];  const void* bg1 = d_in[3];
    const void* Wg2 = d_in[4];  const void* bg2 = d_in[5];
    const void* Wd1 = d_in[6];  const void* bd1 = d_in[7];
    const void* Wd2 = d_in[8];  const void* bd2 = d_in[9];
    const void* mWg1 = d_in[10]; const void* mbg1 = d_in[11];
    const void* mWg2 = d_in[12]; const void* mbg2 = d_in[13];
    const void* mWd1 = d_in[14]; const void* mbd1 = d_in[15];
    const void* mWd2 = d_in[16]; const void* mbd2 = d_in[17];
    char* ws = (char*)d_ws;

    if (ws_size >= A_NEED) {
        // =================== BIG PATH ===================
        unsigned short* FQ    = (unsigned short*)(ws + A_FQ);
        unsigned short* FK    = (unsigned short*)(ws + A_FK);
        unsigned short* WD1T  = (unsigned short*)(ws + A_WD1T);
        unsigned short* MWD1T = (unsigned short*)(ws + A_MWD1T);
        unsigned short* WG1T  = (unsigned short*)(ws + A_WG1T);
        unsigned short* MWG1T = (unsigned short*)(ws + A_MWG1T);
        unsigned short* W2dq  = (unsigned short*)(ws + A_W2DQ);
        unsigned short* W2dk  = (unsigned short*)(ws + A_W2DK);
        unsigned short* W2gq  = (unsigned short*)(ws + A_W2GQ);
        unsigned short* W2gk  = (unsigned short*)(ws + A_W2GK);
        float* rawdq = (float*)(ws + A_RAWDQ);
        float* rawdk = (float*)(ws + A_RAWDK);
        float* rawgq = (float*)(ws + A_RAWGQ);
        float* rawgk = (float*)(ws + A_RAWGK);
        unsigned short* gq = (unsigned short*)(ws + A_GQ);
        unsigned short* gk = (unsigned short*)(ws + A_GK);
        unsigned short* qd = (unsigned short*)(ws + A_QD);
        unsigned short* kd = (unsigned short*)(ws + A_KD);
        unsigned short* mt = (unsigned short*)(ws + A_MT);
        float* pos  = (float*)(ws + A_POS);
        float* lsep = (float*)(ws + A_RAWDQ);   // rawdq region dead after simmatch
        float* lgr  = (float*)(ws + A_LGR);
        int*   flag = (int*)(ws + A_FLAG);

        detect_kernel<<<1, 64, 0, stream>>>((const unsigned short*)feat_q, flag);
        convpool_kernel<<<dim3(4, 128, 2), 256, 0, stream>>>(feat_q, feat_k, FQ, FK, gq, gk, flag);
        transpose4v_kernel<<<dim3(32, 32, 4), 256, 0, stream>>>(
            Wd1, mWd1, Wg1, mWg1, WD1T, MWD1T, WG1T, MWG1T, 2048, 2048, flag);
        transpose4v_kernel<<<dim3(2, 32, 4), 256, 0, stream>>>(
            Wd2, mWd2, Wg2, mWg2, W2dq, W2dk, W2gq, W2gk, 2048, 128, flag);
        zero_kernel<<<1600, 256, 0, stream>>>(rawdq, 409600);
        mega256_kernel<<<dim3(8, 26, 2), 512, 0, stream>>>(
            FQ, FK, gq, gk, WD1T, MWD1T, WG1T, MWG1T,
            W2dq, W2dk, W2gq, W2gk, bd1, mbd1, bg1, mbg1,
            rawdq, rawdk, rawgq, rawgk, flag);
        simmatch_kernel<<<dim3(128, 2), 256, 0, stream>>>(rawdq, rawdk, bd2, mbd2, qd, kd, mt, pos, flag);
        lse_kernel<<<dim3(49, NZSPLIT), 256, 0, stream>>>(qd, mt, lsep);
        lg_kernel<<<16, 128, 0, stream>>>(rawgq, rawgk, bg2, mbg2, lgr, flag);
        final_kernel<<<1, 256, 0, stream>>>(lsep, pos, lgr, (unsigned int*)d_out);
    } else {
        // =================== SMALL PATH ===================
        unsigned short* slotA = (unsigned short*)(ws + B_SLOTA);
        unsigned short* slotB = (unsigned short*)(ws + B_SLOTB);
        unsigned short* W2dq = (unsigned short*)(ws + B_W2DQ);
        unsigned short* W2dk = (unsigned short*)(ws + B_W2DK);
        unsigned short* W2gq = (unsigned short*)(ws + B_W2GQ);
        unsigned short* W2gk = (unsigned short*)(ws + B_W2GK);
        float* rawdq = (float*)(ws + B_RAWDQ);
        float* rawdk = (float*)(ws + B_RAWDK);
        float* rawgq = (float*)(ws + B_RAWGQ);
        float* rawgk = (float*)(ws + B_RAWGK);
        unsigned short* gq = (unsigned short*)(ws + B_GQ);
        unsigned short* gk = (unsigned short*)(ws + B_GK);
        unsigned short* qd = (unsigned short*)(ws + B_QD);
        unsigned short* kd = (unsigned short*)(ws + B_KD);
        unsigned short* mt = (unsigned short*)(ws + B_MT);
        float* pos  = (float*)(ws + B_POS);
        float* lsep = (float*)(ws + B_RAWDQ);   // rawdq region dead after simmatch
        float* lgr  = (float*)(ws + B_LGR);
        int*   flag = (int*)(ws + B_FLAG);

        detect_kernel<<<1, 64, 0, stream>>>((const unsigned short*)feat_q, flag);
        pool_kernel<<<dim3(8, 128, 2), 256, 0, stream>>>(feat_q, feat_k, gq, gk, flag);
        transpose2v_kernel<<<dim3(32, 32, 2), 256, 0, stream>>>(Wg1, mWg1, slotA, slotB, 2048, 2048, flag);
        transpose4v_kernel<<<dim3(2, 32, 4), 256, 0, stream>>>(
            Wd2, mWd2, Wg2, mWg2, W2dq, W2dk, W2gq, W2gk, 2048, 128, flag);
        zero_kernel<<<1600, 256, 0, stream>>>(rawdq, 409600);
        mlp_kernel<<<dim3(16, 1, 2), 256, 0, stream>>>(
            gq, gk, slotA, slotB, W2gq, W2gk, bg1, mbg1, rawgq, rawgk, flag);
        transpose2v_kernel<<<dim3(32, 32, 1), 256, 0, stream>>>(Wd1, Wd1, slotA, slotA, 2048, 2048, flag);
        convert_kernel<<<6272, 256, 0, stream>>>(feat_q, slotB, flag);
        mlp_kernel<<<dim3(16, 49, 1), 256, 0, stream>>>(
            slotB, slotB, slotA, slotA, W2dq, W2dq, bd1, bd1, rawdq, rawdq, flag);
        transpose2v_kernel<<<dim3(32, 32, 1), 256, 0, stream>>>(mWd1, mWd1, slotA, slotA, 2048, 2048, flag);
        convert_kernel<<<6272, 256, 0, stream>>>(feat_k, slotB, flag);
        mlp_kernel<<<dim3(16, 49, 1), 256, 0, stream>>>(
            slotB, slotB, slotA, slotA, W2dk, W2dk, mbd1, mbd1, rawdk, rawdk, flag);
        simmatch_kernel<<<dim3(128, 2), 256, 0, stream>>>(rawdq, rawdk, bd2, mbd2, qd, kd, mt, pos, flag);
        lse_kernel<<<dim3(49, NZSPLIT), 256, 0, stream>>>(qd, mt, lsep);
        lg_kernel<<<16, 128, 0, stream>>>(rawgq, rawgk, bg2, mbg2, lgr, flag);
        final_kernel<<<1, 256, 0, stream>>>(lsep, pos, lgr, (unsigned int*)d_out);
    }
}

// Round 7
// 1051.944 us; speedup vs baseline: 1.0151x; 1.0151x over previous
//
#include <hip/hip_runtime.h>
#include <cstddef>

typedef __bf16 bf16x8 __attribute__((ext_vector_type(8)));
typedef float  f32x4  __attribute__((ext_vector_type(4)));
typedef float  f32x2  __attribute__((ext_vector_type(2)));
typedef unsigned short u16x8 __attribute__((ext_vector_type(8)));
typedef unsigned short u16x4 __attribute__((ext_vector_type(4)));
typedef unsigned short u16x2 __attribute__((ext_vector_type(2)));

__device__ __forceinline__ float b2f(unsigned short u) {
    union { unsigned int i; float f; } v; v.i = ((unsigned int)u) << 16; return v.f;
}
__device__ __forceinline__ unsigned short f2b(float f) {
    union { float f; unsigned int i; } v; v.f = f;
    unsigned int r = v.i + 0x7fffu + ((v.i >> 16) & 1u);
    return (unsigned short)(r >> 16);
}
__device__ __forceinline__ void gl_lds16(const void* g, void* l) {
    __builtin_amdgcn_global_load_lds((const __attribute__((address_space(1))) void*)g,
                                     (__attribute__((address_space(3))) void*)l,
                                     16, 0, 0);
}

// XCD-aware bijective block swizzle (m204 form).
__device__ __forceinline__ void xcd_swizzle(int& bx, int& by, int& bz) {
    unsigned int nx = gridDim.x, ny = gridDim.y;
    unsigned int n = nx * ny * gridDim.z;
    unsigned int lin = blockIdx.x + nx * (blockIdx.y + ny * blockIdx.z);
    unsigned int q = n >> 3, r = n & 7u;
    unsigned int xcd = lin & 7u, off = lin >> 3;
    unsigned int s = (xcd < r) ? (xcd * (q + 1u) + off)
                               : (r * (q + 1u) + (xcd - r) * q + off);
    bx = (int)(s % nx); s /= nx;
    by = (int)(s % ny);
    bz = (int)(s / ny);
}

// ------------------- input dtype detector -------------------
__global__ __launch_bounds__(64) void detect_kernel(const unsigned short* __restrict__ feat,
                                                    int* __restrict__ flag) {
    __shared__ int cnt;
    if (threadIdx.x == 0) cnt = 0;
    __syncthreads();
    int c = 0;
    for (int i = threadIdx.x; i < 256; i += 64) {
        float v = b2f(feat[i]);
        if (fabsf(v) > 100.0f) ++c;
    }
    atomicAdd(&cnt, c);
    __syncthreads();
    if (threadIdx.x == 0) *flag = (cnt > 16) ? 1 : 0;   // 1 => inputs are fp32
}

// ------------------- zero fill -------------------
__global__ __launch_bounds__(256) void zero_kernel(float* __restrict__ p, int n4) {
    int i = blockIdx.x * 256 + threadIdx.x;
    const f32x4 z = {0.f, 0.f, 0.f, 0.f};
    if (i < n4) ((f32x4*)p)[i] = z;
}

// ------------------- BIG PATH: fused convert(feat->bf16) + global pool -------------------
__global__ __launch_bounds__(256) void convpool_kernel(const void* __restrict__ fq,
                                                       const void* __restrict__ fk,
                                                       unsigned short* __restrict__ FQ,
                                                       unsigned short* __restrict__ FK,
                                                       unsigned short* __restrict__ gq,
                                                       unsigned short* __restrict__ gk,
                                                       const int* __restrict__ flagp) {
    int fl = *flagp;
    int b = blockIdx.y;
    const void* src = blockIdx.z ? fk : fq;
    unsigned short* dst = blockIdx.z ? FK : FQ;
    unsigned short* g   = blockIdx.z ? gk : gq;
    int c0 = blockIdx.x * 512 + threadIdx.x * 2;
    float s0 = 0.f, s1 = 0.f;
    if (fl) {
        const float* sf = (const float*)src;
        #pragma unroll 7
        for (int p = 0; p < 49; ++p) {
            size_t idx = ((size_t)b * 49 + p) * 2048 + c0;
            f32x2 v = *(const f32x2*)(sf + idx);
            u16x2 o; o[0] = f2b(v[0]); o[1] = f2b(v[1]);
            s0 += v[0]; s1 += v[1];
            *(u16x2*)(dst + idx) = o;
        }
    } else {
        const unsigned short* su = (const unsigned short*)src;
        #pragma unroll 7
        for (int p = 0; p < 49; ++p) {
            size_t idx = ((size_t)b * 49 + p) * 2048 + c0;
            u16x2 o = *(const u16x2*)(su + idx);
            s0 += b2f(o[0]); s1 += b2f(o[1]);
            *(u16x2*)(dst + idx) = o;
        }
    }
    u16x2 gm; gm[0] = f2b(s0 * (1.0f / 49.0f)); gm[1] = f2b(s1 * (1.0f / 49.0f));
    *(u16x2*)(g + (size_t)b * 2048 + c0) = gm;
}

// ------------------- SMALL PATH: convert feat -> bf16 -------------------
__global__ __launch_bounds__(256) void convert_kernel(const void* __restrict__ in,
                                                      unsigned short* __restrict__ out,
                                                      const int* __restrict__ flagp) {
    int fl = *flagp;
    size_t i = ((size_t)blockIdx.x * 256 + threadIdx.x) * 8;
    if (fl) {
        const float* inf = (const float*)in;
        f32x4 v0 = *(const f32x4*)(inf + i);
        f32x4 v1 = *(const f32x4*)(inf + i + 4);
        u16x8 o;
        o[0]=f2b(v0[0]); o[1]=f2b(v0[1]); o[2]=f2b(v0[2]); o[3]=f2b(v0[3]);
        o[4]=f2b(v1[0]); o[5]=f2b(v1[1]); o[6]=f2b(v1[2]); o[7]=f2b(v1[3]);
        *(u16x8*)(out + i) = o;
    } else {
        *(u16x8*)(out + i) = *(const u16x8*)((const unsigned short*)in + i);
    }
}

// ------------------- SMALL PATH: global average pool -------------------
__global__ __launch_bounds__(256) void pool_kernel(const void* __restrict__ fq,
                                                   const void* __restrict__ fk,
                                                   unsigned short* __restrict__ gq,
                                                   unsigned short* __restrict__ gk,
                                                   const int* __restrict__ flagp) {
    int fl = *flagp;
    int c = blockIdx.x * 256 + threadIdx.x;
    int b = blockIdx.y;
    const void* src = blockIdx.z ? fk : fq;
    unsigned short* dst = blockIdx.z ? gk : gq;
    size_t base = (size_t)b * 49 * 2048 + c;
    float s = 0.f;
    if (fl) {
        const float* sf = (const float*)src;
        #pragma unroll
        for (int p = 0; p < 49; ++p) s += sf[base + (size_t)p * 2048];
    } else {
        const unsigned short* su = (const unsigned short*)src;
        #pragma unroll
        for (int p = 0; p < 49; ++p) s += b2f(su[base + (size_t)p * 2048]);
    }
    dst[(size_t)b * 2048 + c] = f2b(s * (1.0f / 49.0f));
}

// ------------------- 2-way vectorized transpose+convert (64x64 tiles) -------------------
__global__ __launch_bounds__(256) void transpose2v_kernel(
    const void* __restrict__ s0, const void* __restrict__ s1,
    unsigned short* __restrict__ d0, unsigned short* __restrict__ d1,
    int rows, int cols, const int* __restrict__ flagp) {
    int fl = *flagp;
    int z = blockIdx.z;
    const void* in = z ? s1 : s0;
    unsigned short* out = z ? d1 : d0;
    __shared__ unsigned short tile[64 * 72];
    int bx = blockIdx.x * 64, by = blockIdx.y * 64;
    int tr = threadIdx.x >> 3;
    int tc = (threadIdx.x & 7) * 8;
    #pragma unroll
    for (int h = 0; h < 2; ++h) {
        int r = tr + h * 32;
        if (fl) {
            const float* inf = (const float*)in + (size_t)(by + r) * cols + bx + tc;
            f32x4 v0 = *(const f32x4*)inf;
            f32x4 v1 = *(const f32x4*)(inf + 4);
            u16x8 o;
            o[0]=f2b(v0[0]); o[1]=f2b(v0[1]); o[2]=f2b(v0[2]); o[3]=f2b(v0[3]);
            o[4]=f2b(v1[0]); o[5]=f2b(v1[1]); o[6]=f2b(v1[2]); o[7]=f2b(v1[3]);
            *(u16x8*)(tile + r * 72 + tc) = o;
        } else {
            const unsigned short* inu = (const unsigned short*)in + (size_t)(by + r) * cols + bx + tc;
            *(u16x8*)(tile + r * 72 + tc) = *(const u16x8*)inu;
        }
    }
    __syncthreads();
    #pragma unroll
    for (int h = 0; h < 2; ++h) {
        int oc = tr + h * 32;
        u16x8 v;
        #pragma unroll
        for (int j = 0; j < 8; ++j) v[j] = tile[(tc + j) * 72 + oc];
        *(u16x8*)(out + (size_t)(bx + oc) * rows + by + tc) = v;
    }
}

// ------------------- 4-way vectorized transpose+convert -------------------
__global__ __launch_bounds__(256) void transpose4v_kernel(
    const void* __restrict__ s0, const void* __restrict__ s1,
    const void* __restrict__ s2, const void* __restrict__ s3,
    unsigned short* __restrict__ d0, unsigned short* __restrict__ d1,
    unsigned short* __restrict__ d2, unsigned short* __restrict__ d3,
    int rows, int cols, const int* __restrict__ flagp) {
    int fl = *flagp;
    int z = blockIdx.z;
    const void* in = (z == 0) ? s0 : (z == 1) ? s1 : (z == 2) ? s2 : s3;
    unsigned short* out = (z == 0) ? d0 : (z == 1) ? d1 : (z == 2) ? d2 : d3;
    __shared__ unsigned short tile[64 * 72];
    int bx = blockIdx.x * 64, by = blockIdx.y * 64;
    int tr = threadIdx.x >> 3;
    int tc = (threadIdx.x & 7) * 8;
    #pragma unroll
    for (int h = 0; h < 2; ++h) {
        int r = tr + h * 32;
        if (fl) {
            const float* inf = (const float*)in + (size_t)(by + r) * cols + bx + tc;
            f32x4 v0 = *(const f32x4*)inf;
            f32x4 v1 = *(const f32x4*)(inf + 4);
            u16x8 o;
            o[0]=f2b(v0[0]); o[1]=f2b(v0[1]); o[2]=f2b(v0[2]); o[3]=f2b(v0[3]);
            o[4]=f2b(v1[0]); o[5]=f2b(v1[1]); o[6]=f2b(v1[2]); o[7]=f2b(v1[3]);
            *(u16x8*)(tile + r * 72 + tc) = o;
        } else {
            const unsigned short* inu = (const unsigned short*)in + (size_t)(by + r) * cols + bx + tc;
            *(u16x8*)(tile + r * 72 + tc) = *(const u16x8*)inu;
        }
    }
    __syncthreads();
    #pragma unroll
    for (int h = 0; h < 2; ++h) {
        int oc = tr + h * 32;
        u16x8 v;
        #pragma unroll
        for (int j = 0; j < 8; ++j) v[j] = tile[(tc + j) * 72 + oc];
        *(u16x8*)(out + (size_t)(bx + oc) * rows + by + tc) = v;
    }
}

// ======================= 256x256 8-wave 4-phase/K-tile mega GEMM =======================
// T2(XOR k-swizzle)+T3(phase interleave)+T4(counted waits)+T5(setprio).
// Register budget: R4/R5 showed hipcc's __launch_bounds__ 2nd arg does NOT reach
// the allocator (both (512,2) and (512,1) gave identical 128-VGPR spilling code;
// WRITE_SIZE 1.27 GB of scratch stores, MfmaUtil 6.8%). The default heuristic
// targets 4 waves/EU -> 512/4 = 128 VGPRs. Fix: explicit Clang attributes —
// amdgpu_waves_per_eu(2,2) pins the budget at 512/2 = 256 VGPRs/wave, the
// occupancy this kernel actually runs (8 waves, 1 block/CU, LDS-pinned).
__global__ __attribute__((amdgpu_flat_work_group_size(512, 512), amdgpu_waves_per_eu(2, 2)))
void mega256_kernel(
    const unsigned short* __restrict__ FQ, const unsigned short* __restrict__ FK,
    const unsigned short* __restrict__ gq, const unsigned short* __restrict__ gk,
    const unsigned short* __restrict__ WD1T, const unsigned short* __restrict__ MWD1T,
    const unsigned short* __restrict__ WG1T, const unsigned short* __restrict__ MWG1T,
    const unsigned short* __restrict__ W2dq, const unsigned short* __restrict__ W2dk,
    const unsigned short* __restrict__ W2gq, const unsigned short* __restrict__ W2gk,
    const void* __restrict__ bd1, const void* __restrict__ mbd1,
    const void* __restrict__ bg1, const void* __restrict__ mbg1,
    float* __restrict__ rawdq, float* __restrict__ rawdk,
    float* __restrict__ rawgq, float* __restrict__ rawgk,
    const int* __restrict__ flagp)
{
    int fl = *flagp;
    int bx, by, bz;
    xcd_swizzle(bx, by, bz);
    int z = bz;
    const unsigned short *A, *Bt, *W2; const void* b1; float* outp;
    size_t m0;
    if (by < 25) {
        // dense: by<24 full 256 tiles; by==24 tail of 128 rows (6272 = 24*256+128)
        A = z ? FK : FQ;  Bt = z ? MWD1T : WD1T;  W2 = z ? W2dk : W2dq;
        b1 = z ? mbd1 : bd1;  outp = z ? rawdk : rawdq;
        m0 = (size_t)by * 256;
    } else {
        // global head: 128 rows
        A = z ? gk : gq;  Bt = z ? MWG1T : WG1T;  W2 = z ? W2gk : W2gq;
        b1 = z ? mbg1 : bg1;  outp = z ? rawgk : rawgq;
        m0 = 0;
    }
    int mloc = (by >= 24) ? 128 : 256;     // valid local rows (others clamped+discarded)
    size_t n0 = (size_t)bx * 256;

    const int K = 2048;
    __shared__ unsigned short smem[65536];   // 128 KB
    unsigned short* As0v = smem;
    unsigned short* Bs0v = smem + 16384;
    unsigned short* As1v = smem + 32768;
    unsigned short* Bs1v = smem + 49152;
    unsigned short* Hs   = smem;             // phase2: 256 x 72 (aliases bufs, used after K-loop)

    int tid  = threadIdx.x;
    int lane = tid & 63;
    int w    = tid >> 6;                     // 0..7
    int wm = w & 1, wn = w >> 1;             // 2M x 4N wave grid
    int quad = lane >> 4, l16 = lane & 15;
    int lrow = lane >> 3;
    int kc   = (lane & 7) ^ lrow;            // pre-swizzled global k-slot (rule 21)
    int swz  = l16 & 7;

    const unsigned short* gA[4];
    const unsigned short* gB[4];
    int offAB[4];
    #pragma unroll
    for (int c = 0; c < 4; ++c) {
        int ra = (w * 32 + c * 8 + lrow) & (mloc - 1);   // clamp for 128-row tiles
        int rb = w * 32 + c * 8 + lrow;
        gA[c] = A  + (m0 + ra) * (size_t)K + kc * 8;
        gB[c] = Bt + (n0 + rb) * (size_t)K + kc * 8;
        offAB[c] = w * 2048 + c * 512;
    }

    const f32x4 zero4 = {0.f, 0.f, 0.f, 0.f};
    f32x4 acc[8][4];
    #pragma unroll
    for (int i = 0; i < 8; ++i)
        #pragma unroll
        for (int j = 0; j < 4; ++j) acc[i][j] = zero4;
    bf16x8 bfr[4][2];
    bf16x8 af[2][2];

#define STG_A(c, Dst) do { gl_lds16(gA[(c)], (Dst) + offAB[(c)]); gA[(c)] += 64; } while (0)
#define STG_B(c, Dst) do { gl_lds16(gB[(c)], (Dst) + offAB[(c)]); gB[(c)] += 64; } while (0)

#define PH(Acur, Bcur, q, STAGES) do {                                          \
    if ((q) == 0) {                                                             \
        _Pragma("unroll")                                                       \
        for (int nt_ = 0; nt_ < 4; ++nt_) {                                     \
            _Pragma("unroll")                                                   \
            for (int ki_ = 0; ki_ < 2; ++ki_) {                                 \
                int sc_ = (((ki_ * 4) + quad) ^ swz) << 3;                      \
                bfr[nt_][ki_] = *(const bf16x8*)((Bcur) + (wn * 64 + nt_ * 16 + l16) * 64 + sc_); \
            }                                                                   \
        }                                                                       \
    }                                                                           \
    _Pragma("unroll")                                                           \
    for (int i_ = 0; i_ < 2; ++i_) {                                            \
        _Pragma("unroll")                                                       \
        for (int ki_ = 0; ki_ < 2; ++ki_) {                                     \
            int sc_ = (((ki_ * 4) + quad) ^ swz) << 3;                          \
            af[i_][ki_] = *(const bf16x8*)((Acur) + (wm * 128 + (2 * (q) + i_) * 16 + l16) * 64 + sc_); \
        }                                                                       \
    }                                                                           \
    STAGES                                                                      \
    __builtin_amdgcn_s_barrier();                                               \
    asm volatile("s_waitcnt lgkmcnt(0)" ::: "memory");                          \
    __builtin_amdgcn_sched_barrier(0);                                          \
    __builtin_amdgcn_s_setprio(1);                                              \
    _Pragma("unroll")                                                           \
    for (int i_ = 0; i_ < 2; ++i_)                                              \
        _Pragma("unroll")                                                       \
        for (int nt_ = 0; nt_ < 4; ++nt_)                                       \
            _Pragma("unroll")                                                   \
            for (int ki_ = 0; ki_ < 2; ++ki_)                                   \
                acc[2 * (q) + i_][nt_] = __builtin_amdgcn_mfma_f32_16x16x32_bf16(af[i_][ki_], bfr[nt_][ki_], acc[2 * (q) + i_][nt_], 0, 0, 0); \
    __builtin_amdgcn_s_setprio(0);                                              \
    __builtin_amdgcn_s_barrier();                                               \
} while (0)

    // prologue: stage K-tile 0 into buf0 (8 loads/thread in flight)
    STG_A(0, As0v); STG_A(1, As0v); STG_A(2, As0v); STG_A(3, As0v);
    STG_B(0, Bs0v); STG_B(1, Bs0v); STG_B(2, Bs0v); STG_B(3, Bs0v);

    #pragma unroll 1
    for (int tt = 0; tt < 16; ++tt) {
        // ---- even tile: compute buf0, stage t+1 -> buf1 ----
        asm volatile("s_waitcnt vmcnt(0)" ::: "memory");
        __builtin_amdgcn_s_barrier();
        PH(As0v, Bs0v, 0, { STG_A(0, As1v); STG_A(1, As1v); STG_B(0, Bs1v); });
        PH(As0v, Bs0v, 1, { STG_A(2, As1v); STG_A(3, As1v); STG_B(1, Bs1v); });
        PH(As0v, Bs0v, 2, { STG_B(2, Bs1v); STG_B(3, Bs1v); });
        PH(As0v, Bs0v, 3, {});
        // ---- odd tile: compute buf1, stage t+1 -> buf0 (none on last) ----
        asm volatile("s_waitcnt vmcnt(0)" ::: "memory");
        __builtin_amdgcn_s_barrier();
        if (tt < 15) {
            PH(As1v, Bs1v, 0, { STG_A(0, As0v); STG_A(1, As0v); STG_B(0, Bs0v); });
            PH(As1v, Bs1v, 1, { STG_A(2, As0v); STG_A(3, As0v); STG_B(1, Bs0v); });
            PH(As1v, Bs1v, 2, { STG_B(2, Bs0v); STG_B(3, Bs0v); });
            PH(As1v, Bs1v, 3, {});
        } else {
            PH(As1v, Bs1v, 0, {});
            PH(As1v, Bs1v, 1, {});
            PH(As1v, Bs1v, 2, {});
            PH(As1v, Bs1v, 3, {});
        }
    }
#undef PH
#undef STG_A
#undef STG_B

    // ---------------- phase 2: relu(raw1+b1) @ W2T ----------------
    float b1v[4];
    #pragma unroll
    for (int nt = 0; nt < 4; ++nt) {
        int col = (int)n0 + wn * 64 + nt * 16 + l16;
        b1v[nt] = fl ? ((const float*)b1)[col] : b2f(((const unsigned short*)b1)[col]);
    }
    // pack H into bf16 now: frees the 128 acc VGPRs before the chunk loop
    u16x4 hbf[8][4];
    #pragma unroll
    for (int mt = 0; mt < 8; ++mt)
        #pragma unroll
        for (int nt = 0; nt < 4; ++nt)
            #pragma unroll
            for (int r = 0; r < 4; ++r)
                hbf[mt][nt][r] = f2b(fmaxf(acc[mt][nt][r] + b1v[nt], 0.f));

    int wm2 = w >> 1, wn2 = w & 1;           // 4M x 2N retile for GEMM2
    f32x4 acc2[4][4];
    #pragma unroll
    for (int i = 0; i < 4; ++i)
        #pragma unroll
        for (int j = 0; j < 4; ++j) acc2[i][j] = zero4;

    const unsigned short* W2g = W2;          // W2T: 128 x 2048
    #pragma unroll
    for (int j = 0; j < 4; ++j) {
        if (wn == j) {   // this wave's 64 hidden cols become the K-chunk
            #pragma unroll
            for (int mt = 0; mt < 8; ++mt)
                #pragma unroll
                for (int nt = 0; nt < 4; ++nt)
                    #pragma unroll
                    for (int r = 0; r < 4; ++r)
                        Hs[(wm * 128 + mt * 16 + quad * 4 + r) * 72 + nt * 16 + l16] = hbf[mt][nt][r];
        }
        asm volatile("s_waitcnt lgkmcnt(0)" ::: "memory");
        __builtin_amdgcn_s_barrier();
        #pragma unroll
        for (int ki = 0; ki < 2; ++ki) {
            bf16x8 ha[4], wb[4];
            #pragma unroll
            for (int mt = 0; mt < 4; ++mt)
                ha[mt] = *(const bf16x8*)(Hs + (wm2 * 64 + mt * 16 + l16) * 72 + ki * 32 + quad * 8);
            #pragma unroll
            for (int et = 0; et < 4; ++et)
                wb[et] = *(const bf16x8*)(W2g + (size_t)(wn2 * 64 + et * 16 + l16) * 2048
                                          + n0 + j * 64 + ki * 32 + quad * 8);
            #pragma unroll
            for (int mt = 0; mt < 4; ++mt)
                #pragma unroll
                for (int et = 0; et < 4; ++et)
                    acc2[mt][et] = __builtin_amdgcn_mfma_f32_16x16x32_bf16(ha[mt], wb[et], acc2[mt][et], 0, 0, 0);
        }
        asm volatile("s_waitcnt lgkmcnt(0)" ::: "memory");
        __builtin_amdgcn_s_barrier();        // WAR before next chunk's H overwrite
    }

    #pragma unroll
    for (int et = 0; et < 4; ++et) {
        int col = wn2 * 64 + et * 16 + l16;
        #pragma unroll
        for (int mt = 0; mt < 4; ++mt)
            #pragma unroll
            for (int r = 0; r < 4; ++r) {
                int rl = wm2 * 64 + mt * 16 + quad * 4 + r;
                if (rl < mloc)
                    atomicAdd(&outp[(m0 + rl) * 128 + col], acc2[mt][et][r]);
            }
    }
}

// ======================= MLP core (small path, unchanged) =======================
__device__ __forceinline__ void mlp_body(
    const unsigned short* __restrict__ A, const unsigned short* __restrict__ Bt,
    const unsigned short* __restrict__ W2, const void* __restrict__ b1,
    float* __restrict__ outp, size_t m0, size_t n0, int fl)
{
    const int K = 2048;
    __shared__ unsigned short smem[32768];   // 64 KB
    unsigned short* As0 = smem;
    unsigned short* Bs0 = smem + 8192;
    unsigned short* As1 = smem + 16384;
    unsigned short* Bs1 = smem + 24576;
    unsigned short* W2s = smem;
    unsigned short* Hs  = smem + 8192;

    int tid  = threadIdx.x;
    int lane = tid & 63;
    int w    = tid >> 6;
    int wm = w & 1, wn = w >> 1;
    int quad = lane >> 4, l16 = lane & 15;
    int lrow = lane >> 3;
    int kc   = (lane & 7) ^ lrow;

    const unsigned short* gA[4];
    const unsigned short* gB[4];
    int off[4];
    #pragma unroll
    for (int c = 0; c < 4; ++c) {
        int row = w * 32 + c * 8 + lrow;
        gA[c] = A  + (m0 + row) * (size_t)K + kc * 8;
        gB[c] = Bt + (n0 + row) * (size_t)K + kc * 8;
        off[c] = w * 2048 + c * 512;
    }

    const f32x4 zero4 = {0.f, 0.f, 0.f, 0.f};
    f32x4 acc[4][4];
    #pragma unroll
    for (int i = 0; i < 4; ++i)
        #pragma unroll
        for (int j = 0; j < 4; ++j) acc[i][j] = zero4;

    int swz = l16 & 7;

#define STAGE(Ad, Bd) do { \
    _Pragma("unroll") \
    for (int c = 0; c < 4; ++c) { gl_lds16(gA[c], (Ad) + off[c]); gA[c] += 64; } \
    _Pragma("unroll") \
    for (int c = 0; c < 4; ++c) { gl_lds16(gB[c], (Bd) + off[c]); gB[c] += 64; } \
} while (0)

#define CSTEP(Asrc, Bsrc) do { \
    _Pragma("unroll") \
    for (int k0 = 0; k0 < 64; k0 += 32) { \
        bf16x8 af[4], bfr[4]; \
        _Pragma("unroll") \
        for (int mt = 0; mt < 4; ++mt) { \
            int row = wm * 64 + mt * 16 + l16; \
            int sc  = (((k0 >> 3) + quad) ^ swz) << 3; \
            af[mt] = *(const bf16x8*)((Asrc) + row * 64 + sc); \
        } \
        _Pragma("unroll") \
        for (int nt = 0; nt < 4; ++nt) { \
            int row = wn * 64 + nt * 16 + l16; \
            int sc  = (((k0 >> 3) + quad) ^ swz) << 3; \
            bfr[nt] = *(const bf16x8*)((Bsrc) + row * 64 + sc); \
        } \
        __builtin_amdgcn_s_setprio(1); \
        _Pragma("unroll") \
        for (int mt = 0; mt < 4; ++mt) \
            _Pragma("unroll") \
            for (int nt = 0; nt < 4; ++nt) \
                acc[mt][nt] = __builtin_amdgcn_mfma_f32_16x16x32_bf16(af[mt], bfr[nt], acc[mt][nt], 0, 0, 0); \
        __builtin_amdgcn_s_setprio(0); \
    } \
} while (0)

    STAGE(As0, Bs0);
    #pragma unroll 1
    for (int kb2 = 0; kb2 < 16; ++kb2) {
        STAGE(As1, Bs1);
        asm volatile("s_waitcnt vmcnt(8)" ::: "memory");
        __builtin_amdgcn_s_barrier();
        __builtin_amdgcn_sched_barrier(0);
        CSTEP(As0, Bs0);
        asm volatile("s_waitcnt lgkmcnt(0)" ::: "memory");
        __builtin_amdgcn_sched_barrier(0);
        __builtin_amdgcn_s_barrier();
        if (kb2 < 15) {
            STAGE(As0, Bs0);
            asm volatile("s_waitcnt vmcnt(8)" ::: "memory");
        } else {
            asm volatile("s_waitcnt vmcnt(0)" ::: "memory");
        }
        __builtin_amdgcn_s_barrier();
        __builtin_amdgcn_sched_barrier(0);
        CSTEP(As1, Bs1);
        asm volatile("s_waitcnt lgkmcnt(0)" ::: "memory");
        __builtin_amdgcn_sched_barrier(0);
        __builtin_amdgcn_s_barrier();
    }
#undef STAGE
#undef CSTEP

    float b1v[4];
    #pragma unroll
    for (int nt = 0; nt < 4; ++nt) {
        int col = (int)n0 + wn * 64 + nt * 16 + l16;
        b1v[nt] = fl ? ((const float*)b1)[col] : b2f(((const unsigned short*)b1)[col]);
    }

    f32x4 acc2[4][4];
    #pragma unroll
    for (int i = 0; i < 4; ++i)
        #pragma unroll
        for (int j = 0; j < 4; ++j) acc2[i][j] = zero4;

    #pragma unroll
    for (int hf = 0; hf < 2; ++hf) {
        __syncthreads();
        if (wn == hf) {
            #pragma unroll
            for (int mt = 0; mt < 4; ++mt)
                #pragma unroll
                for (int nt = 0; nt < 4; ++nt)
                    #pragma unroll
                    for (int r = 0; r < 4; ++r) {
                        float v = fmaxf(acc[mt][nt][r] + b1v[nt], 0.f);
                        Hs[(wm * 64 + mt * 16 + quad * 4 + r) * 72 + nt * 16 + l16] = f2b(v);
                    }
        } else {
            #pragma unroll
            for (int c = 0; c < 8; ++c) {
                const unsigned short* g = W2 + (size_t)(wm * 64 + c * 8 + lrow) * 2048
                                          + n0 + hf * 64 + kc * 8;
                gl_lds16(g, W2s + wm * 4096 + c * 512);
            }
        }
        __syncthreads();
        #pragma unroll
        for (int k0 = 0; k0 < 64; k0 += 32) {
            bf16x8 ha[4], wb[4];
            #pragma unroll
            for (int mt = 0; mt < 4; ++mt)
                ha[mt] = *(const bf16x8*)(Hs + (wm * 64 + mt * 16 + l16) * 72 + k0 + quad * 8);
            #pragma unroll
            for (int et = 0; et < 4; ++et) {
                int row = wn * 64 + et * 16 + l16;
                int sc  = (((k0 >> 3) + quad) ^ swz) << 3;
                wb[et] = *(const bf16x8*)(W2s + row * 64 + sc);
            }
            #pragma unroll
            for (int mt = 0; mt < 4; ++mt)
                #pragma unroll
                for (int et = 0; et < 4; ++et)
                    acc2[mt][et] = __builtin_amdgcn_mfma_f32_16x16x32_bf16(ha[mt], wb[et], acc2[mt][et], 0, 0, 0);
        }
    }

    #pragma unroll
    for (int et = 0; et < 4; ++et) {
        int col = wn * 64 + et * 16 + l16;
        #pragma unroll
        for (int mt = 0; mt < 4; ++mt)
            #pragma unroll
            for (int r = 0; r < 4; ++r) {
                size_t row = m0 + wm * 64 + mt * 16 + quad * 4 + r;
                atomicAdd(&outp[row * 128 + col], acc2[mt][et][r]);
            }
    }
}

// ---- SMALL PATH: pair mlp (z selects pointer pair) ----
__global__ __launch_bounds__(256) void mlp_kernel(
    const unsigned short* __restrict__ A0, const unsigned short* __restrict__ A1,
    const unsigned short* __restrict__ Bt0, const unsigned short* __restrict__ Bt1,
    const unsigned short* __restrict__ W20, const unsigned short* __restrict__ W21,
    const void* __restrict__ b10, const void* __restrict__ b11,
    float* __restrict__ out0, float* __restrict__ out1,
    const int* __restrict__ flagp)
{
    int fl = *flagp;
    int bx, by, bz;
    xcd_swizzle(bx, by, bz);
    int z  = bz;
    mlp_body(z ? A1 : A0, z ? Bt1 : Bt0, z ? W21 : W20, z ? b11 : b10,
             z ? out1 : out0, (size_t)by * 128, (size_t)bx * 128, fl);
}

// ---- fused dense: bias + l2norm (writes qd/kd) + sim 49x49 + argmax + matched + pos ----
__global__ __launch_bounds__(256) void simmatch_kernel(
    const float* __restrict__ rawdq, const float* __restrict__ rawdk,
    const void* __restrict__ bd2, const void* __restrict__ mbd2,
    unsigned short* __restrict__ qd, unsigned short* __restrict__ kd,
    unsigned short* __restrict__ matched, float* __restrict__ pos,
    const int* __restrict__ flagp) {
    int fl = *flagp;
    __shared__ float f1s[49 * 128];
    __shared__ float f2s[49 * 128];
    int b = blockIdx.x;
    int half = blockIdx.y;
    int t = threadIdx.x;
    size_t base = (size_t)b * 49 * 128;

    int rr = t >> 2, jq = t & 3;
    if (rr < 49) {
        #pragma unroll
        for (int br = 0; br < 2; ++br) {
            const float* raw = br ? rawdk : rawdq;
            const void* bias = br ? mbd2 : bd2;
            unsigned short* outg = br ? kd : qd;
            float* fs = br ? f2s : f1s;
            size_t idx = base + (size_t)rr * 128 + jq * 32;
            float x[32];
            float ss = 0.f;
            #pragma unroll
            for (int c = 0; c < 32; ++c) {
                float bv = fl ? ((const float*)bias)[jq * 32 + c]
                              : b2f(((const unsigned short*)bias)[jq * 32 + c]);
                x[c] = raw[idx + c] + bv;
                ss += x[c] * x[c];
            }
            ss += __shfl_xor(ss, 1); ss += __shfl_xor(ss, 2);
            float rs = rsqrtf(fmaxf(ss, 1e-12f));
            #pragma unroll
            for (int c = 0; c < 32; ++c) {
                unsigned short us = f2b(x[c] * rs);
                if (half == 0) outg[idx + c] = us;
                fs[rr * 128 + jq * 32 + c] = b2f(us);
            }
        }
    }
    __syncthreads();

    int i0 = t >> 2, q4 = t & 3;
    int i = half * 25 + i0;
    int ilim = half ? 24 : 25;
    if (i0 < ilim) {
        int mlo = q4 * 13;
        int mhi = mlo + 13; if (mhi > 49) mhi = 49;
        float best = -1e30f; int bi = 1 << 20;
        const f32x4* va = (const f32x4*)(f1s + i * 128);
        for (int m = mlo; m < mhi; ++m) {
            const f32x4* vb = (const f32x4*)(f2s + m * 128);
            float d = 0.f;
            #pragma unroll
            for (int j = 0; j < 32; ++j) {
                f32x4 a = va[j], bb = vb[j];
                d += a[0]*bb[0] + a[1]*bb[1] + a[2]*bb[2] + a[3]*bb[3];
            }
            if (d > best) { best = d; bi = m; }
        }
        #pragma unroll
        for (int off = 1; off < 4; off <<= 1) {
            float ov = __shfl_xor(best, off);
            int   oi = __shfl_xor(bi, off);
            if (ov > best || (ov == best && oi < bi)) { best = ov; bi = oi; }
        }
        if (q4 == 0) pos[b * 49 + i] = best * 5.0f;
        for (int j = q4 * 32; j < q4 * 32 + 32; ++j)
            matched[base + (size_t)i * 128 + j] = f2b(f2s[bi * 128 + j]);
    }
}

// ------------------- fused dense InfoNCE sum-of-exp, col-split x14 -------------------
#define KS 136
#define NZSPLIT 14
__global__ __launch_bounds__(256) void lse_kernel(const unsigned short* __restrict__ qd,
                                                  const unsigned short* __restrict__ matched,
                                                  float* __restrict__ lsep) {
    __shared__ unsigned short As[128 * KS];
    __shared__ unsigned short Bs[64 * KS];
    __shared__ float rsum[128];
    int tid  = threadIdx.x;
    int lane = tid & 63, wave = tid >> 6;
    int wm = wave & 1, wn = wave >> 1;
    int quad = lane >> 4, l16 = lane & 15;
    size_t m0 = (size_t)blockIdx.x * 128;
    int z = blockIdx.y;

    #pragma unroll
    for (int i = 0; i < 8; ++i) {
        int l = tid + 256 * i;
        int row = l >> 4, ko = (l & 15) << 3;
        u16x8 v = *(const u16x8*)(qd + (m0 + row) * 128 + ko);
        *(u16x8*)(As + row * KS + ko) = v;
    }
    if (tid < 128) rsum[tid] = 0.f;

    float rs[4][4];
    #pragma unroll
    for (int mt = 0; mt < 4; ++mt)
        #pragma unroll
        for (int r = 0; r < 4; ++r) rs[mt][r] = 0.f;

    const f32x4 zero4 = {0.f, 0.f, 0.f, 0.f};
    int nlo = z * 448, nhi = nlo + 448;
    for (int n0 = nlo; n0 < nhi; n0 += 64) {
        __syncthreads();
        #pragma unroll
        for (int i = 0; i < 4; ++i) {
            int l = tid + 256 * i;
            int row = l >> 4, ko = (l & 15) << 3;
            u16x8 v = *(const u16x8*)(matched + (size_t)(n0 + row) * 128 + ko);
            *(u16x8*)(Bs + row * KS + ko) = v;
        }
        __syncthreads();
        f32x4 acc[4][2];
        #pragma unroll
        for (int mt = 0; mt < 4; ++mt) { acc[mt][0] = zero4; acc[mt][1] = zero4; }
        #pragma unroll
        for (int k0 = 0; k0 < 128; k0 += 32) {
            bf16x8 af[4], bfr[2];
            #pragma unroll
            for (int mt = 0; mt < 4; ++mt)
                af[mt] = *(const bf16x8*)(As + (wm * 64 + mt * 16 + l16) * KS + k0 + quad * 8);
            #pragma unroll
            for (int nt = 0; nt < 2; ++nt)
                bfr[nt] = *(const bf16x8*)(Bs + (wn * 32 + nt * 16 + l16) * KS + k0 + quad * 8);
            #pragma unroll
            for (int mt = 0; mt < 4; ++mt)
                #pragma unroll
                for (int nt = 0; nt < 2; ++nt)
                    acc[mt][nt] = __builtin_amdgcn_mfma_f32_16x16x32_bf16(af[mt], bfr[nt], acc[mt][nt], 0, 0, 0);
        }
        #pragma unroll
        for (int mt = 0; mt < 4; ++mt)
            #pragma unroll
            for (int r = 0; r < 4; ++r)
                rs[mt][r] += __expf(acc[mt][0][r] * 5.0f) + __expf(acc[mt][1][r] * 5.0f);
    }
    #pragma unroll
    for (int mt = 0; mt < 4; ++mt)
        #pragma unroll
        for (int r = 0; r < 4; ++r) {
            float v = rs[mt][r];
            v += __shfl_xor(v, 1); v += __shfl_xor(v, 2);
            v += __shfl_xor(v, 4); v += __shfl_xor(v, 8);
            if (l16 == 0) atomicAdd(&rsum[wm * 64 + mt * 16 + quad * 4 + r], v);
        }
    __syncthreads();
    if (tid < 128) lsep[(size_t)z * 6272 + m0 + tid] = rsum[tid];
}

// ---- fused global: bias + l2norm (on the fly) + InfoNCE row term ----
__global__ __launch_bounds__(128) void lg_kernel(const float* __restrict__ rawgq,
                                                 const float* __restrict__ rawgk,
                                                 const void* __restrict__ bg2,
                                                 const void* __restrict__ mbg2,
                                                 float* __restrict__ lgrow,
                                                 const int* __restrict__ flagp) {
    int fl = *flagp;
    __shared__ float ksf[128 * 128];
    __shared__ float qsf[8 * 128];
    int t = threadIdx.x;
    int rbase = blockIdx.x * 8;
    {
        const float* rk = rawgk + (size_t)t * 128;
        float ss = 0.f;
        for (int c = 0; c < 128; ++c) {
            float bv = fl ? ((const float*)mbg2)[c] : b2f(((const unsigned short*)mbg2)[c]);
            float xx = rk[c] + bv;
            ss += xx * xx;
        }
        float rsv = rsqrtf(fmaxf(ss, 1e-12f));
        for (int c = 0; c < 128; ++c) {
            float bv = fl ? ((const float*)mbg2)[c] : b2f(((const unsigned short*)mbg2)[c]);
            ksf[t * 128 + c] = b2f(f2b((rk[c] + bv) * rsv));
        }
    }
    if (t < 8) {
        const float* rq = rawgq + (size_t)(rbase + t) * 128;
        float ss = 0.f;
        for (int c = 0; c < 128; ++c) {
            float bv = fl ? ((const float*)bg2)[c] : b2f(((const unsigned short*)bg2)[c]);
            float xx = rq[c] + bv;
            ss += xx * xx;
        }
        float rsv = rsqrtf(fmaxf(ss, 1e-12f));
        for (int c = 0; c < 128; ++c) {
            float bv = fl ? ((const float*)bg2)[c] : b2f(((const unsigned short*)bg2)[c]);
            qsf[t * 128 + c] = b2f(f2b((rq[c] + bv) * rsv));
        }
    }
    __syncthreads();
    int rl = t >> 4, jg = t & 15;
    int row = rbase + rl;
    float se = 0.f, diag = 0.f;
    for (int jj = 0; jj < 8; ++jj) {
        int j = jg * 8 + jj;
        float d = 0.f;
        #pragma unroll 8
        for (int c = 0; c < 128; ++c) d += qsf[rl * 128 + c] * ksf[j * 128 + c];
        d *= 5.0f;
        se += __expf(d);
        if (j == row) diag = d;
    }
    #pragma unroll
    for (int off = 1; off < 16; off <<= 1) { se += __shfl_xor(se, off); diag += __shfl_xor(diag, off); }
    if (jg == 0) lgrow[row] = logf(se) - diag;
}

// ------------------- final combine, dtype-hedged output -------------------
__global__ __launch_bounds__(256) void final_kernel(const float* __restrict__ lsep,
                                                    const float* __restrict__ pos,
                                                    const float* __restrict__ lgrow,
                                                    unsigned int* __restrict__ out) {
    int t = threadIdx.x;
    float s = 0.f;
    for (int i = t; i < 6272; i += 256) {
        float se = 0.f;
        #pragma unroll
        for (int zz = 0; zz < NZSPLIT; ++zz) se += lsep[zz * 6272 + i];
        s += logf(se) - pos[i];
    }
    float g = (t < 128) ? lgrow[t] : 0.f;
    #pragma unroll
    for (int off = 32; off >= 1; off >>= 1) { s += __shfl_xor(s, off); g += __shfl_xor(g, off); }
    __shared__ float p8[8];
    if ((t & 63) == 0) { p8[t >> 6] = s; p8[4 + (t >> 6)] = g; }
    __syncthreads();
    if (t == 0) {
        float ld  = (p8[0] + p8[1] + p8[2] + p8[3]) * (1.0f / 6272.0f);
        float lg  = (p8[4] + p8[5] + p8[6] + p8[7]) * (1.0f / 128.0f);
        float total = 0.5f * lg + 0.5f * ld;
        unsigned int L = f2b(total);
        union { float f; unsigned int u; } tb; tb.f = total;
        unsigned int base = (tb.u & 0xFFFF0000u) | L;
        unsigned int bu = base; float be = 1e30f;
        #pragma unroll
        for (int d = -1; d <= 1; ++d) {
            unsigned int c = base + ((unsigned int)d << 16);
            union { unsigned int u; float f; } cv; cv.u = c;
            float e = fabsf(cv.f - total);
            if (e < be) { be = e; bu = c; }
        }
        out[0] = bu;
    }
}

// ------------------- BIG layout (needs 99,652,608 B) -------------------
#define A_FQ     ((size_t)0)
#define A_FK     ((size_t)25690112)
#define A_WD1T   ((size_t)51380224)
#define A_MWD1T  ((size_t)59768832)
#define A_WG1T   ((size_t)68157440)
#define A_MWG1T  ((size_t)76546048)
#define A_W2DQ   ((size_t)84934656)
#define A_W2DK   ((size_t)85458944)
#define A_W2GQ   ((size_t)85983232)
#define A_W2GK   ((size_t)86507520)
#define A_RAWDQ  ((size_t)87031808)
#define A_RAWDK  ((size_t)90243072)
#define A_RAWGQ  ((size_t)93454336)
#define A_RAWGK  ((size_t)93519872)
#define A_GQ     ((size_t)93585408)
#define A_GK     ((size_t)94109696)
#define A_QD     ((size_t)94633984)
#define A_KD     ((size_t)96239616)
#define A_MT     ((size_t)97845248)
#define A_POS    ((size_t)99450880)
#define A_LSEP   ((size_t)99475968)
#define A_LGR    ((size_t)99651584)
#define A_FLAG   ((size_t)99652096)
#define A_NEED   ((size_t)99652608)
// lsep (14 x 6272 f32 = 343 KB) lives in the rawdq region (dead after simmatch).

// ------------------- SMALL layout (peak 43.78 MB) -------------------
#define B_SLOTA  ((size_t)0)
#define B_QD     ((size_t)0)
#define B_KD     ((size_t)1605632)
#define B_MT     ((size_t)3211264)
#define B_SLOTB  ((size_t)8388608)
#define B_W2DQ   ((size_t)34078720)
#define B_W2DK   ((size_t)34603008)
#define B_W2GQ   ((size_t)35127296)
#define B_W2GK   ((size_t)35651584)
#define B_RAWDQ  ((size_t)36175872)
#define B_RAWDK  ((size_t)39387136)
#define B_RAWGQ  ((size_t)42598400)
#define B_RAWGK  ((size_t)42663936)
#define B_GQ     ((size_t)42729472)
#define B_GK     ((size_t)43253760)
#define B_POS    ((size_t)42729472)
#define B_LSEP   ((size_t)42754560)
#define B_LGR    ((size_t)42930176)
#define B_FLAG   ((size_t)42930688)

extern "C" void kernel_launch(void* const* d_in, const int* in_sizes, int n_in,
                              void* d_out, int out_size, void* d_ws, size_t ws_size,
                              hipStream_t stream) {
    (void)in_sizes; (void)n_in; (void)out_size;
    const void* feat_q = d_in[0];
    const void* feat_k = d_in[1];
    const void* Wg1 = d_in[2];  const void* bg1 = d_in[3];
    const void* Wg2 = d_in[4];  const void* bg2 = d_in[5];
    const void* Wd1 = d_in[6];  const void* bd1 = d_in[7];
    const void* Wd2 = d_in[8];  const void* bd2 = d_in[9];
    const void* mWg1 = d_in[10]; const void* mbg1 = d_in[11];
    const void* mWg2 = d_in[12]; const void* mbg2 = d_in[13];
    const void* mWd1 = d_in[14]; const void* mbd1 = d_in[15];
    const void* mWd2 = d_in[16]; const void* mbd2 = d_in[17];
    char* ws = (char*)d_ws;

    if (ws_size >= A_NEED) {
        // =================== BIG PATH ===================
        unsigned short* FQ    = (unsigned short*)(ws + A_FQ);
        unsigned short* FK    = (unsigned short*)(ws + A_FK);
        unsigned short* WD1T  = (unsigned short*)(ws + A_WD1T);
        unsigned short* MWD1T = (unsigned short*)(ws + A_MWD1T);
        unsigned short* WG1T  = (unsigned short*)(ws + A_WG1T);
        unsigned short* MWG1T = (unsigned short*)(ws + A_MWG1T);
        unsigned short* W2dq  = (unsigned short*)(ws + A_W2DQ);
        unsigned short* W2dk  = (unsigned short*)(ws + A_W2DK);
        unsigned short* W2gq  = (unsigned short*)(ws + A_W2GQ);
        unsigned short* W2gk  = (unsigned short*)(ws + A_W2GK);
        float* rawdq = (float*)(ws + A_RAWDQ);
        float* rawdk = (float*)(ws + A_RAWDK);
        float* rawgq = (float*)(ws + A_RAWGQ);
        float* rawgk = (float*)(ws + A_RAWGK);
        unsigned short* gq = (unsigned short*)(ws + A_GQ);
        unsigned short* gk = (unsigned short*)(ws + A_GK);
        unsigned short* qd = (unsigned short*)(ws + A_QD);
        unsigned short* kd = (unsigned short*)(ws + A_KD);
        unsigned short* mt = (unsigned short*)(ws + A_MT);
        float* pos  = (float*)(ws + A_POS);
        float* lsep = (float*)(ws + A_RAWDQ);   // rawdq region dead after simmatch
        float* lgr  = (float*)(ws + A_LGR);
        int*   flag = (int*)(ws + A_FLAG);

        detect_kernel<<<1, 64, 0, stream>>>((const unsigned short*)feat_q, flag);
        convpool_kernel<<<dim3(4, 128, 2), 256, 0, stream>>>(feat_q, feat_k, FQ, FK, gq, gk, flag);
        transpose4v_kernel<<<dim3(32, 32, 4), 256, 0, stream>>>(
            Wd1, mWd1, Wg1, mWg1, WD1T, MWD1T, WG1T, MWG1T, 2048, 2048, flag);
        transpose4v_kernel<<<dim3(2, 32, 4), 256, 0, stream>>>(
            Wd2, mWd2, Wg2, mWg2, W2dq, W2dk, W2gq, W2gk, 2048, 128, flag);
        zero_kernel<<<1600, 256, 0, stream>>>(rawdq, 409600);
        mega256_kernel<<<dim3(8, 26, 2), 512, 0, stream>>>(
            FQ, FK, gq, gk, WD1T, MWD1T, WG1T, MWG1T,
            W2dq, W2dk, W2gq, W2gk, bd1, mbd1, bg1, mbg1,
            rawdq, rawdk, rawgq, rawgk, flag);
        simmatch_kernel<<<dim3(128, 2), 256, 0, stream>>>(rawdq, rawdk, bd2, mbd2, qd, kd, mt, pos, flag);
        lse_kernel<<<dim3(49, NZSPLIT), 256, 0, stream>>>(qd, mt, lsep);
        lg_kernel<<<16, 128, 0, stream>>>(rawgq, rawgk, bg2, mbg2, lgr, flag);
        final_kernel<<<1, 256, 0, stream>>>(lsep, pos, lgr, (unsigned int*)d_out);
    } else {
        // =================== SMALL PATH ===================
        unsigned short* slotA = (unsigned short*)(ws + B_SLOTA);
        unsigned short* slotB = (unsigned short*)(ws + B_SLOTB);
        unsigned short* W2dq = (unsigned short*)(ws + B_W2DQ);
        unsigned short* W2dk = (unsigned short*)(ws + B_W2DK);
        unsigned short* W2gq = (unsigned short*)(ws + B_W2GQ);
        unsigned short* W2gk = (unsigned short*)(ws + B_W2GK);
        float* rawdq = (float*)(ws + B_RAWDQ);
        float* rawdk = (float*)(ws + B_RAWDK);
        float* rawgq = (float*)(ws + B_RAWGQ);
        float* rawgk = (float*)(ws + B_RAWGK);
        unsigned short* gq = (unsigned short*)(ws + B_GQ);
        unsigned short* gk = (unsigned short*)(ws + B_GK);
        unsigned short* qd = (unsigned short*)(ws + B_QD);
        unsigned short* kd = (unsigned short*)(ws + B_KD);
        unsigned short* mt = (unsigned short*)(ws + B_MT);
        float* pos  = (float*)(ws + B_POS);
        float* lsep = (float*)(ws + B_RAWDQ);   // rawdq region dead after simmatch
        float* lgr  = (float*)(ws + B_LGR);
        int*   flag = (int*)(ws + B_FLAG);

        detect_kernel<<<1, 64, 0, stream>>>((const unsigned short*)feat_q, flag);
        pool_kernel<<<dim3(8, 128, 2), 256, 0, stream>>>(feat_q, feat_k, gq, gk, flag);
        transpose2v_kernel<<<dim3(32, 32, 2), 256, 0, stream>>>(Wg1, mWg1, slotA, slotB, 2048, 2048, flag);
        transpose4v_kernel<<<dim3(2, 32, 4), 256, 0, stream>>>(
            Wd2, mWd2, Wg2, mWg2, W2dq, W2dk, W2gq, W2gk, 2048, 128, flag);
        zero_kernel<<<1600, 256, 0, stream>>>(rawdq, 409600);
        mlp_kernel<<<dim3(16, 1, 2), 256, 0, stream>>>(
            gq, gk, slotA, slotB, W2gq, W2gk, bg1, mbg1, rawgq, rawgk, flag);
        transpose2v_kernel<<<dim3(32, 32, 1), 256, 0, stream>>>(Wd1, Wd1, slotA, slotA, 2048, 2048, flag);
        convert_kernel<<<6272, 256, 0, stream>>>(feat_q, slotB, flag);
        mlp_kernel<<<dim3(16, 49, 1), 256, 0, stream>>>(
            slotB, slotB, slotA, slotA, W2dq, W2dq, bd1, bd1, rawdq, rawdq, flag);
        transpose2v_kernel<<<dim3(32, 32, 1), 256, 0, stream>>>(mWd1, mWd1, slotA, slotA, 2048, 2048, flag);
        convert_kernel<<<6272, 256, 0, stream>>>(feat_k, slotB, flag);
        mlp_kernel<<<dim3(16, 49, 1), 256, 0, stream>>>(
            slotB, slotB, slotA, slotA, W2dk, W2dk, mbd1, mbd1, rawdk, rawdk, flag);
        simmatch_kernel<<<dim3(128, 2), 256, 0, stream>>>(rawdq, rawdk, bd2, mbd2, qd, kd, mt, pos, flag);
        lse_kernel<<<dim3(49, NZSPLIT), 256, 0, stream>>>(qd, mt, lsep);
        lg_kernel<<<16, 128, 0, stream>>>(rawgq, rawgk, bg2, mbg2, lgr, flag);
        final_kernel<<<1, 256, 0, stream>>>(lsep, pos, lgr, (unsigned int*)d_out);
    }
}

// Round 8
// 531.727 us; speedup vs baseline: 2.0083x; 1.9784x over previous
//
#include <hip/hip_runtime.h>
#include <cstddef>

typedef __bf16 bf16x8 __attribute__((ext_vector_type(8)));
typedef float  f32x4  __attribute__((ext_vector_type(4)));
typedef float  f32x2  __attribute__((ext_vector_type(2)));
typedef unsigned short u16x8 __attribute__((ext_vector_type(8)));
typedef unsigned short u16x4 __attribute__((ext_vector_type(4)));
typedef unsigned short u16x2 __attribute__((ext_vector_type(2)));

__device__ __forceinline__ float b2f(unsigned short u) {
    union { unsigned int i; float f; } v; v.i = ((unsigned int)u) << 16; return v.f;
}
__device__ __forceinline__ unsigned short f2b(float f) {
    union { float f; unsigned int i; } v; v.f = f;
    unsigned int r = v.i + 0x7fffu + ((v.i >> 16) & 1u);
    return (unsigned short)(r >> 16);
}
__device__ __forceinline__ void gl_lds16(const void* g, void* l) {
    __builtin_amdgcn_global_load_lds((const __attribute__((address_space(1))) void*)g,
                                     (__attribute__((address_space(3))) void*)l,
                                     16, 0, 0);
}

// XCD-aware bijective block swizzle (m204 form).
__device__ __forceinline__ void xcd_swizzle(int& bx, int& by, int& bz) {
    unsigned int nx = gridDim.x, ny = gridDim.y;
    unsigned int n = nx * ny * gridDim.z;
    unsigned int lin = blockIdx.x + nx * (blockIdx.y + ny * blockIdx.z);
    unsigned int q = n >> 3, r = n & 7u;
    unsigned int xcd = lin & 7u, off = lin >> 3;
    unsigned int s = (xcd < r) ? (xcd * (q + 1u) + off)
                               : (r * (q + 1u) + (xcd - r) * q + off);
    bx = (int)(s % nx); s /= nx;
    by = (int)(s % ny);
    bz = (int)(s / ny);
}

// ------------------- input dtype detector -------------------
__global__ __launch_bounds__(64) void detect_kernel(const unsigned short* __restrict__ feat,
                                                    int* __restrict__ flag) {
    __shared__ int cnt;
    if (threadIdx.x == 0) cnt = 0;
    __syncthreads();
    int c = 0;
    for (int i = threadIdx.x; i < 256; i += 64) {
        float v = b2f(feat[i]);
        if (fabsf(v) > 100.0f) ++c;
    }
    atomicAdd(&cnt, c);
    __syncthreads();
    if (threadIdx.x == 0) *flag = (cnt > 16) ? 1 : 0;   // 1 => inputs are fp32
}

// ------------------- zero fill -------------------
__global__ __launch_bounds__(256) void zero_kernel(float* __restrict__ p, int n4) {
    int i = blockIdx.x * 256 + threadIdx.x;
    const f32x4 z = {0.f, 0.f, 0.f, 0.f};
    if (i < n4) ((f32x4*)p)[i] = z;
}

// ------------------- BIG PATH: fused convert(feat->bf16) + global pool -------------------
// Grid (4, 128, 2). Thread owns 2 consecutive c; loops p=0..48 (unroll 7 for load ILP).
__global__ __launch_bounds__(256) void convpool_kernel(const void* __restrict__ fq,
                                                       const void* __restrict__ fk,
                                                       unsigned short* __restrict__ FQ,
                                                       unsigned short* __restrict__ FK,
                                                       unsigned short* __restrict__ gq,
                                                       unsigned short* __restrict__ gk,
                                                       const int* __restrict__ flagp) {
    int fl = *flagp;
    int b = blockIdx.y;
    const void* src = blockIdx.z ? fk : fq;
    unsigned short* dst = blockIdx.z ? FK : FQ;
    unsigned short* g   = blockIdx.z ? gk : gq;
    int c0 = blockIdx.x * 512 + threadIdx.x * 2;
    float s0 = 0.f, s1 = 0.f;
    if (fl) {
        const float* sf = (const float*)src;
        #pragma unroll 7
        for (int p = 0; p < 49; ++p) {
            size_t idx = ((size_t)b * 49 + p) * 2048 + c0;
            f32x2 v = *(const f32x2*)(sf + idx);
            u16x2 o; o[0] = f2b(v[0]); o[1] = f2b(v[1]);
            s0 += v[0]; s1 += v[1];
            *(u16x2*)(dst + idx) = o;
        }
    } else {
        const unsigned short* su = (const unsigned short*)src;
        #pragma unroll 7
        for (int p = 0; p < 49; ++p) {
            size_t idx = ((size_t)b * 49 + p) * 2048 + c0;
            u16x2 o = *(const u16x2*)(su + idx);
            s0 += b2f(o[0]); s1 += b2f(o[1]);
            *(u16x2*)(dst + idx) = o;
        }
    }
    u16x2 gm; gm[0] = f2b(s0 * (1.0f / 49.0f)); gm[1] = f2b(s1 * (1.0f / 49.0f));
    *(u16x2*)(g + (size_t)b * 2048 + c0) = gm;
}

// ------------------- SMALL PATH: convert feat -> bf16 -------------------
__global__ __launch_bounds__(256) void convert_kernel(const void* __restrict__ in,
                                                      unsigned short* __restrict__ out,
                                                      const int* __restrict__ flagp) {
    int fl = *flagp;
    size_t i = ((size_t)blockIdx.x * 256 + threadIdx.x) * 8;
    if (fl) {
        const float* inf = (const float*)in;
        f32x4 v0 = *(const f32x4*)(inf + i);
        f32x4 v1 = *(const f32x4*)(inf + i + 4);
        u16x8 o;
        o[0]=f2b(v0[0]); o[1]=f2b(v0[1]); o[2]=f2b(v0[2]); o[3]=f2b(v0[3]);
        o[4]=f2b(v1[0]); o[5]=f2b(v1[1]); o[6]=f2b(v1[2]); o[7]=f2b(v1[3]);
        *(u16x8*)(out + i) = o;
    } else {
        *(u16x8*)(out + i) = *(const u16x8*)((const unsigned short*)in + i);
    }
}

// ------------------- SMALL PATH: global average pool -------------------
__global__ __launch_bounds__(256) void pool_kernel(const void* __restrict__ fq,
                                                   const void* __restrict__ fk,
                                                   unsigned short* __restrict__ gq,
                                                   unsigned short* __restrict__ gk,
                                                   const int* __restrict__ flagp) {
    int fl = *flagp;
    int c = blockIdx.x * 256 + threadIdx.x;
    int b = blockIdx.y;
    const void* src = blockIdx.z ? fk : fq;
    unsigned short* dst = blockIdx.z ? gk : gq;
    size_t base = (size_t)b * 49 * 2048 + c;
    float s = 0.f;
    if (fl) {
        const float* sf = (const float*)src;
        #pragma unroll
        for (int p = 0; p < 49; ++p) s += sf[base + (size_t)p * 2048];
    } else {
        const unsigned short* su = (const unsigned short*)src;
        #pragma unroll
        for (int p = 0; p < 49; ++p) s += b2f(su[base + (size_t)p * 2048]);
    }
    dst[(size_t)b * 2048 + c] = f2b(s * (1.0f / 49.0f));
}

// ------------------- 2-way vectorized transpose+convert (64x64 tiles) -------------------
__global__ __launch_bounds__(256) void transpose2v_kernel(
    const void* __restrict__ s0, const void* __restrict__ s1,
    unsigned short* __restrict__ d0, unsigned short* __restrict__ d1,
    int rows, int cols, const int* __restrict__ flagp) {
    int fl = *flagp;
    int z = blockIdx.z;
    const void* in = z ? s1 : s0;
    unsigned short* out = z ? d1 : d0;
    __shared__ unsigned short tile[64 * 72];
    int bx = blockIdx.x * 64, by = blockIdx.y * 64;
    int tr = threadIdx.x >> 3;
    int tc = (threadIdx.x & 7) * 8;
    #pragma unroll
    for (int h = 0; h < 2; ++h) {
        int r = tr + h * 32;
        if (fl) {
            const float* inf = (const float*)in + (size_t)(by + r) * cols + bx + tc;
            f32x4 v0 = *(const f32x4*)inf;
            f32x4 v1 = *(const f32x4*)(inf + 4);
            u16x8 o;
            o[0]=f2b(v0[0]); o[1]=f2b(v0[1]); o[2]=f2b(v0[2]); o[3]=f2b(v0[3]);
            o[4]=f2b(v1[0]); o[5]=f2b(v1[1]); o[6]=f2b(v1[2]); o[7]=f2b(v1[3]);
            *(u16x8*)(tile + r * 72 + tc) = o;
        } else {
            const unsigned short* inu = (const unsigned short*)in + (size_t)(by + r) * cols + bx + tc;
            *(u16x8*)(tile + r * 72 + tc) = *(const u16x8*)inu;
        }
    }
    __syncthreads();
    #pragma unroll
    for (int h = 0; h < 2; ++h) {
        int oc = tr + h * 32;
        u16x8 v;
        #pragma unroll
        for (int j = 0; j < 8; ++j) v[j] = tile[(tc + j) * 72 + oc];
        *(u16x8*)(out + (size_t)(bx + oc) * rows + by + tc) = v;
    }
}

// ------------------- 4-way vectorized transpose+convert -------------------
__global__ __launch_bounds__(256) void transpose4v_kernel(
    const void* __restrict__ s0, const void* __restrict__ s1,
    const void* __restrict__ s2, const void* __restrict__ s3,
    unsigned short* __restrict__ d0, unsigned short* __restrict__ d1,
    unsigned short* __restrict__ d2, unsigned short* __restrict__ d3,
    int rows, int cols, const int* __restrict__ flagp) {
    int fl = *flagp;
    int z = blockIdx.z;
    const void* in = (z == 0) ? s0 : (z == 1) ? s1 : (z == 2) ? s2 : s3;
    unsigned short* out = (z == 0) ? d0 : (z == 1) ? d1 : (z == 2) ? d2 : d3;
    __shared__ unsigned short tile[64 * 72];
    int bx = blockIdx.x * 64, by = blockIdx.y * 64;
    int tr = threadIdx.x >> 3;
    int tc = (threadIdx.x & 7) * 8;
    #pragma unroll
    for (int h = 0; h < 2; ++h) {
        int r = tr + h * 32;
        if (fl) {
            const float* inf = (const float*)in + (size_t)(by + r) * cols + bx + tc;
            f32x4 v0 = *(const f32x4*)inf;
            f32x4 v1 = *(const f32x4*)(inf + 4);
            u16x8 o;
            o[0]=f2b(v0[0]); o[1]=f2b(v0[1]); o[2]=f2b(v0[2]); o[3]=f2b(v0[3]);
            o[4]=f2b(v1[0]); o[5]=f2b(v1[1]); o[6]=f2b(v1[2]); o[7]=f2b(v1[3]);
            *(u16x8*)(tile + r * 72 + tc) = o;
        } else {
            const unsigned short* inu = (const unsigned short*)in + (size_t)(by + r) * cols + bx + tc;
            *(u16x8*)(tile + r * 72 + tc) = *(const u16x8*)inu;
        }
    }
    __syncthreads();
    #pragma unroll
    for (int h = 0; h < 2; ++h) {
        int oc = tr + h * 32;
        u16x8 v;
        #pragma unroll
        for (int j = 0; j < 8; ++j) v[j] = tile[(tc + j) * 72 + oc];
        *(u16x8*)(out + (size_t)(bx + oc) * rows + by + tc) = v;
    }
}

// ======================= MLP core (shared device function) =======================
// K-loop: double-buffered with COUNTED vmcnt (T4) + raw barriers + setprio (T5).
// Per half-step: STAGE(next) -> vmcnt(8) [wait only the OLD tile's 8 loads,
// leaving the 8 just-issued in flight across the barrier] -> barrier ->
// ds_read+MFMA -> lgkmcnt(0) -> WAR barrier.
// NOTE (R4-R7): the 256^2/512-thread port of this loop is blocked by the
// toolchain pinning 512-thread kernels to 128 VGPRs (acc spills; ~700us);
// __launch_bounds__ 2nd arg and amdgpu_waves_per_eu both fail to raise it.
// This 256-thread form (VGPR 108, no spill) is the verified optimum.
__device__ __forceinline__ void mlp_body(
    const unsigned short* __restrict__ A, const unsigned short* __restrict__ Bt,
    const unsigned short* __restrict__ W2, const void* __restrict__ b1,
    float* __restrict__ outp, size_t m0, size_t n0, int fl)
{
    const int K = 2048;
    __shared__ unsigned short smem[32768];   // 64 KB
    unsigned short* As0 = smem;
    unsigned short* Bs0 = smem + 8192;
    unsigned short* As1 = smem + 16384;
    unsigned short* Bs1 = smem + 24576;
    unsigned short* W2s = smem;              // phase 2 aliases buf0 A
    unsigned short* Hs  = smem + 8192;       // phase 2: 128 x 72

    int tid  = threadIdx.x;
    int lane = tid & 63;
    int w    = tid >> 6;
    int wm = w & 1, wn = w >> 1;
    int quad = lane >> 4, l16 = lane & 15;
    int lrow = lane >> 3;
    int kc   = (lane & 7) ^ lrow;

    const unsigned short* gA[4];
    const unsigned short* gB[4];
    int off[4];
    #pragma unroll
    for (int c = 0; c < 4; ++c) {
        int row = w * 32 + c * 8 + lrow;
        gA[c] = A  + (m0 + row) * (size_t)K + kc * 8;
        gB[c] = Bt + (n0 + row) * (size_t)K + kc * 8;
        off[c] = w * 2048 + c * 512;
    }

    const f32x4 zero4 = {0.f, 0.f, 0.f, 0.f};
    f32x4 acc[4][4];
    #pragma unroll
    for (int i = 0; i < 4; ++i)
        #pragma unroll
        for (int j = 0; j < 4; ++j) acc[i][j] = zero4;

    int swz = l16 & 7;

#define STAGE(Ad, Bd) do { \
    _Pragma("unroll") \
    for (int c = 0; c < 4; ++c) { gl_lds16(gA[c], (Ad) + off[c]); gA[c] += 64; } \
    _Pragma("unroll") \
    for (int c = 0; c < 4; ++c) { gl_lds16(gB[c], (Bd) + off[c]); gB[c] += 64; } \
} while (0)

#define CSTEP(Asrc, Bsrc) do { \
    _Pragma("unroll") \
    for (int k0 = 0; k0 < 64; k0 += 32) { \
        bf16x8 af[4], bfr[4]; \
        _Pragma("unroll") \
        for (int mt = 0; mt < 4; ++mt) { \
            int row = wm * 64 + mt * 16 + l16; \
            int sc  = (((k0 >> 3) + quad) ^ swz) << 3; \
            af[mt] = *(const bf16x8*)((Asrc) + row * 64 + sc); \
        } \
        _Pragma("unroll") \
        for (int nt = 0; nt < 4; ++nt) { \
            int row = wn * 64 + nt * 16 + l16; \
            int sc  = (((k0 >> 3) + quad) ^ swz) << 3; \
            bfr[nt] = *(const bf16x8*)((Bsrc) + row * 64 + sc); \
        } \
        __builtin_amdgcn_s_setprio(1); \
        _Pragma("unroll") \
        for (int mt = 0; mt < 4; ++mt) \
            _Pragma("unroll") \
            for (int nt = 0; nt < 4; ++nt) \
                acc[mt][nt] = __builtin_amdgcn_mfma_f32_16x16x32_bf16(af[mt], bfr[nt], acc[mt][nt], 0, 0, 0); \
        __builtin_amdgcn_s_setprio(0); \
    } \
} while (0)

    // prologue: stage K[0:64) into buf0 (8 loads in flight per wave)
    STAGE(As0, Bs0);
    #pragma unroll 1
    for (int kb2 = 0; kb2 < 16; ++kb2) {
        // ---- half A: prefetch buf1, compute buf0 ----
        STAGE(As1, Bs1);                                    // 16 in flight
        asm volatile("s_waitcnt vmcnt(8)" ::: "memory");    // buf0 ready (this wave)
        __builtin_amdgcn_s_barrier();                       // buf0 ready (all waves)
        __builtin_amdgcn_sched_barrier(0);
        CSTEP(As0, Bs0);
        asm volatile("s_waitcnt lgkmcnt(0)" ::: "memory");
        __builtin_amdgcn_sched_barrier(0);
        __builtin_amdgcn_s_barrier();                       // WAR: all done reading buf0
        // ---- half B: prefetch buf0, compute buf1 ----
        if (kb2 < 15) {
            STAGE(As0, Bs0);                                // 16 in flight
            asm volatile("s_waitcnt vmcnt(8)" ::: "memory");// buf1 ready
        } else {
            asm volatile("s_waitcnt vmcnt(0)" ::: "memory");// drain tail
        }
        __builtin_amdgcn_s_barrier();
        __builtin_amdgcn_sched_barrier(0);
        CSTEP(As1, Bs1);
        asm volatile("s_waitcnt lgkmcnt(0)" ::: "memory");
        __builtin_amdgcn_sched_barrier(0);
        __builtin_amdgcn_s_barrier();                       // WAR: all done reading buf1
    }
#undef STAGE
#undef CSTEP

    float b1v[4];
    #pragma unroll
    for (int nt = 0; nt < 4; ++nt) {
        int col = (int)n0 + wn * 64 + nt * 16 + l16;
        b1v[nt] = fl ? ((const float*)b1)[col] : b2f(((const unsigned short*)b1)[col]);
    }

    f32x4 acc2[4][4];
    #pragma unroll
    for (int i = 0; i < 4; ++i)
        #pragma unroll
        for (int j = 0; j < 4; ++j) acc2[i][j] = zero4;

    #pragma unroll
    for (int hf = 0; hf < 2; ++hf) {
        __syncthreads();
        if (wn == hf) {
            #pragma unroll
            for (int mt = 0; mt < 4; ++mt)
                #pragma unroll
                for (int nt = 0; nt < 4; ++nt)
                    #pragma unroll
                    for (int r = 0; r < 4; ++r) {
                        float v = fmaxf(acc[mt][nt][r] + b1v[nt], 0.f);
                        Hs[(wm * 64 + mt * 16 + quad * 4 + r) * 72 + nt * 16 + l16] = f2b(v);
                    }
        } else {
            #pragma unroll
            for (int c = 0; c < 8; ++c) {
                const unsigned short* g = W2 + (size_t)(wm * 64 + c * 8 + lrow) * 2048
                                          + n0 + hf * 64 + kc * 8;
                gl_lds16(g, W2s + wm * 4096 + c * 512);
            }
        }
        __syncthreads();
        #pragma unroll
        for (int k0 = 0; k0 < 64; k0 += 32) {
            bf16x8 ha[4], wb[4];
            #pragma unroll
            for (int mt = 0; mt < 4; ++mt)
                ha[mt] = *(const bf16x8*)(Hs + (wm * 64 + mt * 16 + l16) * 72 + k0 + quad * 8);
            #pragma unroll
            for (int et = 0; et < 4; ++et) {
                int row = wn * 64 + et * 16 + l16;
                int sc  = (((k0 >> 3) + quad) ^ swz) << 3;
                wb[et] = *(const bf16x8*)(W2s + row * 64 + sc);
            }
            #pragma unroll
            for (int mt = 0; mt < 4; ++mt)
                #pragma unroll
                for (int et = 0; et < 4; ++et)
                    acc2[mt][et] = __builtin_amdgcn_mfma_f32_16x16x32_bf16(ha[mt], wb[et], acc2[mt][et], 0, 0, 0);
        }
    }

    #pragma unroll
    for (int et = 0; et < 4; ++et) {
        int col = wn * 64 + et * 16 + l16;
        #pragma unroll
        for (int mt = 0; mt < 4; ++mt)
            #pragma unroll
            for (int r = 0; r < 4; ++r) {
                size_t row = m0 + wm * 64 + mt * 16 + quad * 4 + r;
                atomicAdd(&outp[row * 128 + col], acc2[mt][et][r]);
            }
    }
}

// ---- BIG PATH: mega mlp, grid (16, 50, 2): y<49 dense strips, y=49 global head ----
__global__ __launch_bounds__(256) void mlp_mega_kernel(
    const unsigned short* __restrict__ FQ, const unsigned short* __restrict__ FK,
    const unsigned short* __restrict__ gq, const unsigned short* __restrict__ gk,
    const unsigned short* __restrict__ WD1T, const unsigned short* __restrict__ MWD1T,
    const unsigned short* __restrict__ WG1T, const unsigned short* __restrict__ MWG1T,
    const unsigned short* __restrict__ W2dq, const unsigned short* __restrict__ W2dk,
    const unsigned short* __restrict__ W2gq, const unsigned short* __restrict__ W2gk,
    const void* __restrict__ bd1, const void* __restrict__ mbd1,
    const void* __restrict__ bg1, const void* __restrict__ mbg1,
    float* __restrict__ rawdq, float* __restrict__ rawdk,
    float* __restrict__ rawgq, float* __restrict__ rawgk,
    const int* __restrict__ flagp)
{
    int fl = *flagp;
    int bx, by, bz;
    xcd_swizzle(bx, by, bz);
    int z = bz;
    int isg = (by == 49);
    const unsigned short *A, *Bt, *W2; const void* b1; float* outp;
    if (!isg) {
        A = z ? FK : FQ;  Bt = z ? MWD1T : WD1T;  W2 = z ? W2dk : W2dq;
        b1 = z ? mbd1 : bd1;  outp = z ? rawdk : rawdq;
    } else {
        A = z ? gk : gq;  Bt = z ? MWG1T : WG1T;  W2 = z ? W2gk : W2gq;
        b1 = z ? mbg1 : bg1;  outp = z ? rawgk : rawgq;
    }
    size_t m0 = isg ? 0 : (size_t)by * 128;
    size_t n0 = (size_t)bx * 128;
    mlp_body(A, Bt, W2, b1, outp, m0, n0, fl);
}

// ---- SMALL PATH: pair mlp (z selects pointer pair) ----
__global__ __launch_bounds__(256) void mlp_kernel(
    const unsigned short* __restrict__ A0, const unsigned short* __restrict__ A1,
    const unsigned short* __restrict__ Bt0, const unsigned short* __restrict__ Bt1,
    const unsigned short* __restrict__ W20, const unsigned short* __restrict__ W21,
    const void* __restrict__ b10, const void* __restrict__ b11,
    float* __restrict__ out0, float* __restrict__ out1,
    const int* __restrict__ flagp)
{
    int fl = *flagp;
    int bx, by, bz;
    xcd_swizzle(bx, by, bz);
    int z  = bz;
    mlp_body(z ? A1 : A0, z ? Bt1 : Bt0, z ? W21 : W20, z ? b11 : b10,
             z ? out1 : out0, (size_t)by * 128, (size_t)bx * 128, fl);
}

// ---- fused dense: bias + l2norm (writes qd/kd) + sim 49x49 + argmax + matched + pos ----
// Grid (128, 2): y splits the 49 query rows 25/24 across two blocks (phase-1 norm
// duplicated; qd/kd global stores gated to y==0) -> 256 blocks = 1 block/CU.
__global__ __launch_bounds__(256) void simmatch_kernel(
    const float* __restrict__ rawdq, const float* __restrict__ rawdk,
    const void* __restrict__ bd2, const void* __restrict__ mbd2,
    unsigned short* __restrict__ qd, unsigned short* __restrict__ kd,
    unsigned short* __restrict__ matched, float* __restrict__ pos,
    const int* __restrict__ flagp) {
    int fl = *flagp;
    __shared__ float f1s[49 * 128];
    __shared__ float f2s[49 * 128];
    int b = blockIdx.x;
    int half = blockIdx.y;
    int t = threadIdx.x;
    size_t base = (size_t)b * 49 * 128;

    int rr = t >> 2, jq = t & 3;
    if (rr < 49) {
        #pragma unroll
        for (int br = 0; br < 2; ++br) {
            const float* raw = br ? rawdk : rawdq;
            const void* bias = br ? mbd2 : bd2;
            unsigned short* outg = br ? kd : qd;
            float* fs = br ? f2s : f1s;
            size_t idx = base + (size_t)rr * 128 + jq * 32;
            float x[32];
            float ss = 0.f;
            #pragma unroll
            for (int c = 0; c < 32; ++c) {
                float bv = fl ? ((const float*)bias)[jq * 32 + c]
                              : b2f(((const unsigned short*)bias)[jq * 32 + c]);
                x[c] = raw[idx + c] + bv;
                ss += x[c] * x[c];
            }
            ss += __shfl_xor(ss, 1); ss += __shfl_xor(ss, 2);
            float rs = rsqrtf(fmaxf(ss, 1e-12f));
            #pragma unroll
            for (int c = 0; c < 32; ++c) {
                unsigned short us = f2b(x[c] * rs);
                if (half == 0) outg[idx + c] = us;
                fs[rr * 128 + jq * 32 + c] = b2f(us);
            }
        }
    }
    __syncthreads();

    int i0 = t >> 2, q4 = t & 3;
    int i = half * 25 + i0;
    int ilim = half ? 24 : 25;
    if (i0 < ilim) {
        int mlo = q4 * 13;
        int mhi = mlo + 13; if (mhi > 49) mhi = 49;
        float best = -1e30f; int bi = 1 << 20;
        const f32x4* va = (const f32x4*)(f1s + i * 128);
        for (int m = mlo; m < mhi; ++m) {
            const f32x4* vb = (const f32x4*)(f2s + m * 128);
            float d = 0.f;
            #pragma unroll
            for (int j = 0; j < 32; ++j) {
                f32x4 a = va[j], bb = vb[j];
                d += a[0]*bb[0] + a[1]*bb[1] + a[2]*bb[2] + a[3]*bb[3];
            }
            if (d > best) { best = d; bi = m; }
        }
        #pragma unroll
        for (int off = 1; off < 4; off <<= 1) {
            float ov = __shfl_xor(best, off);
            int   oi = __shfl_xor(bi, off);
            if (ov > best || (ov == best && oi < bi)) { best = ov; bi = oi; }
        }
        if (q4 == 0) pos[b * 49 + i] = best * 5.0f;
        for (int j = q4 * 32; j < q4 * 32 + 32; ++j)
            matched[base + (size_t)i * 128 + j] = f2b(f2s[bi * 128 + j]);
    }
}

// ------------------- fused dense InfoNCE sum-of-exp, col-split x14 -------------------
#define KS 136
#define NZSPLIT 14
__global__ __launch_bounds__(256) void lse_kernel(const unsigned short* __restrict__ qd,
                                                  const unsigned short* __restrict__ matched,
                                                  float* __restrict__ lsep) {
    __shared__ unsigned short As[128 * KS];
    __shared__ unsigned short Bs[64 * KS];
    __shared__ float rsum[128];
    int tid  = threadIdx.x;
    int lane = tid & 63, wave = tid >> 6;
    int wm = wave & 1, wn = wave >> 1;
    int quad = lane >> 4, l16 = lane & 15;
    size_t m0 = (size_t)blockIdx.x * 128;
    int z = blockIdx.y;

    #pragma unroll
    for (int i = 0; i < 8; ++i) {
        int l = tid + 256 * i;
        int row = l >> 4, ko = (l & 15) << 3;
        u16x8 v = *(const u16x8*)(qd + (m0 + row) * 128 + ko);
        *(u16x8*)(As + row * KS + ko) = v;
    }
    if (tid < 128) rsum[tid] = 0.f;

    float rs[4][4];
    #pragma unroll
    for (int mt = 0; mt < 4; ++mt)
        #pragma unroll
        for (int r = 0; r < 4; ++r) rs[mt][r] = 0.f;

    const f32x4 zero4 = {0.f, 0.f, 0.f, 0.f};
    int nlo = z * 448, nhi = nlo + 448;
    for (int n0 = nlo; n0 < nhi; n0 += 64) {
        __syncthreads();
        #pragma unroll
        for (int i = 0; i < 4; ++i) {
            int l = tid + 256 * i;
            int row = l >> 4, ko = (l & 15) << 3;
            u16x8 v = *(const u16x8*)(matched + (size_t)(n0 + row) * 128 + ko);
            *(u16x8*)(Bs + row * KS + ko) = v;
        }
        __syncthreads();
        f32x4 acc[4][2];
        #pragma unroll
        for (int mt = 0; mt < 4; ++mt) { acc[mt][0] = zero4; acc[mt][1] = zero4; }
        #pragma unroll
        for (int k0 = 0; k0 < 128; k0 += 32) {
            bf16x8 af[4], bfr[2];
            #pragma unroll
            for (int mt = 0; mt < 4; ++mt)
                af[mt] = *(const bf16x8*)(As + (wm * 64 + mt * 16 + l16) * KS + k0 + quad * 8);
            #pragma unroll
            for (int nt = 0; nt < 2; ++nt)
                bfr[nt] = *(const bf16x8*)(Bs + (wn * 32 + nt * 16 + l16) * KS + k0 + quad * 8);
            #pragma unroll
            for (int mt = 0; mt < 4; ++mt)
                #pragma unroll
                for (int nt = 0; nt < 2; ++nt)
                    acc[mt][nt] = __builtin_amdgcn_mfma_f32_16x16x32_bf16(af[mt], bfr[nt], acc[mt][nt], 0, 0, 0);
        }
        #pragma unroll
        for (int mt = 0; mt < 4; ++mt)
            #pragma unroll
            for (int r = 0; r < 4; ++r)
                rs[mt][r] += __expf(acc[mt][0][r] * 5.0f) + __expf(acc[mt][1][r] * 5.0f);
    }
    #pragma unroll
    for (int mt = 0; mt < 4; ++mt)
        #pragma unroll
        for (int r = 0; r < 4; ++r) {
            float v = rs[mt][r];
            v += __shfl_xor(v, 1); v += __shfl_xor(v, 2);
            v += __shfl_xor(v, 4); v += __shfl_xor(v, 8);
            if (l16 == 0) atomicAdd(&rsum[wm * 64 + mt * 16 + quad * 4 + r], v);
        }
    __syncthreads();
    if (tid < 128) lsep[(size_t)z * 6272 + m0 + tid] = rsum[tid];
}

// ---- fused global: bias + l2norm (on the fly) + InfoNCE row term ----
__global__ __launch_bounds__(128) void lg_kernel(const float* __restrict__ rawgq,
                                                 const float* __restrict__ rawgk,
                                                 const void* __restrict__ bg2,
                                                 const void* __restrict__ mbg2,
                                                 float* __restrict__ lgrow,
                                                 const int* __restrict__ flagp) {
    int fl = *flagp;
    __shared__ float ksf[128 * 128];
    __shared__ float qsf[8 * 128];
    int t = threadIdx.x;
    int rbase = blockIdx.x * 8;
    {
        const float* rk = rawgk + (size_t)t * 128;
        float ss = 0.f;
        for (int c = 0; c < 128; ++c) {
            float bv = fl ? ((const float*)mbg2)[c] : b2f(((const unsigned short*)mbg2)[c]);
            float xx = rk[c] + bv;
            ss += xx * xx;
        }
        float rsv = rsqrtf(fmaxf(ss, 1e-12f));
        for (int c = 0; c < 128; ++c) {
            float bv = fl ? ((const float*)mbg2)[c] : b2f(((const unsigned short*)mbg2)[c]);
            ksf[t * 128 + c] = b2f(f2b((rk[c] + bv) * rsv));
        }
    }
    if (t < 8) {
        const float* rq = rawgq + (size_t)(rbase + t) * 128;
        float ss = 0.f;
        for (int c = 0; c < 128; ++c) {
            float bv = fl ? ((const float*)bg2)[c] : b2f(((const unsigned short*)bg2)[c]);
            float xx = rq[c] + bv;
            ss += xx * xx;
        }
        float rsv = rsqrtf(fmaxf(ss, 1e-12f));
        for (int c = 0; c < 128; ++c) {
            float bv = fl ? ((const float*)bg2)[c] : b2f(((const unsigned short*)bg2)[c]);
            qsf[t * 128 + c] = b2f(f2b((rq[c] + bv) * rsv));
        }
    }
    __syncthreads();
    int rl = t >> 4, jg = t & 15;
    int row = rbase + rl;
    float se = 0.f, diag = 0.f;
    for (int jj = 0; jj < 8; ++jj) {
        int j = jg * 8 + jj;
        float d = 0.f;
        #pragma unroll 8
        for (int c = 0; c < 128; ++c) d += qsf[rl * 128 + c] * ksf[j * 128 + c];
        d *= 5.0f;
        se += __expf(d);
        if (j == row) diag = d;
    }
    #pragma unroll
    for (int off = 1; off < 16; off <<= 1) { se += __shfl_xor(se, off); diag += __shfl_xor(diag, off); }
    if (jg == 0) lgrow[row] = logf(se) - diag;
}

// ------------------- final combine, dtype-hedged output -------------------
__global__ __launch_bounds__(256) void final_kernel(const float* __restrict__ lsep,
                                                    const float* __restrict__ pos,
                                                    const float* __restrict__ lgrow,
                                                    unsigned int* __restrict__ out) {
    int t = threadIdx.x;
    float s = 0.f;
    for (int i = t; i < 6272; i += 256) {
        float se = 0.f;
        #pragma unroll
        for (int zz = 0; zz < NZSPLIT; ++zz) se += lsep[zz * 6272 + i];
        s += logf(se) - pos[i];
    }
    float g = (t < 128) ? lgrow[t] : 0.f;
    #pragma unroll
    for (int off = 32; off >= 1; off >>= 1) { s += __shfl_xor(s, off); g += __shfl_xor(g, off); }
    __shared__ float p8[8];
    if ((t & 63) == 0) { p8[t >> 6] = s; p8[4 + (t >> 6)] = g; }
    __syncthreads();
    if (t == 0) {
        float ld  = (p8[0] + p8[1] + p8[2] + p8[3]) * (1.0f / 6272.0f);
        float lg  = (p8[4] + p8[5] + p8[6] + p8[7]) * (1.0f / 128.0f);
        float total = 0.5f * lg + 0.5f * ld;
        unsigned int L = f2b(total);
        union { float f; unsigned int u; } tb; tb.f = total;
        unsigned int base = (tb.u & 0xFFFF0000u) | L;
        unsigned int bu = base; float be = 1e30f;
        #pragma unroll
        for (int d = -1; d <= 1; ++d) {
            unsigned int c = base + ((unsigned int)d << 16);
            union { unsigned int u; float f; } cv; cv.u = c;
            float e = fabsf(cv.f - total);
            if (e < be) { be = e; bu = c; }
        }
        out[0] = bu;
    }
}

// ------------------- BIG layout (needs 99,652,608 B) -------------------
#define A_FQ     ((size_t)0)
#define A_FK     ((size_t)25690112)
#define A_WD1T   ((size_t)51380224)
#define A_MWD1T  ((size_t)59768832)
#define A_WG1T   ((size_t)68157440)
#define A_MWG1T  ((size_t)76546048)
#define A_W2DQ   ((size_t)84934656)
#define A_W2DK   ((size_t)85458944)
#define A_W2GQ   ((size_t)85983232)
#define A_W2GK   ((size_t)86507520)
#define A_RAWDQ  ((size_t)87031808)
#define A_RAWDK  ((size_t)90243072)
#define A_RAWGQ  ((size_t)93454336)
#define A_RAWGK  ((size_t)93519872)
#define A_GQ     ((size_t)93585408)
#define A_GK     ((size_t)94109696)
#define A_QD     ((size_t)94633984)
#define A_KD     ((size_t)96239616)
#define A_MT     ((size_t)97845248)
#define A_POS    ((size_t)99450880)
#define A_LSEP   ((size_t)99475968)
#define A_LGR    ((size_t)99651584)
#define A_FLAG   ((size_t)99652096)
#define A_NEED   ((size_t)99652608)
// lsep (14 slices x 6272 f32 = 343 KB) lives in the rawdq region, which is
// dead after simmatch_kernel consumes it -> no layout growth, no ws_size risk.

// ------------------- SMALL layout (peak 43.78 MB) -------------------
#define B_SLOTA  ((size_t)0)
#define B_QD     ((size_t)0)
#define B_KD     ((size_t)1605632)
#define B_MT     ((size_t)3211264)
#define B_SLOTB  ((size_t)8388608)
#define B_W2DQ   ((size_t)34078720)
#define B_W2DK   ((size_t)34603008)
#define B_W2GQ   ((size_t)35127296)
#define B_W2GK   ((size_t)35651584)
#define B_RAWDQ  ((size_t)36175872)
#define B_RAWDK  ((size_t)39387136)
#define B_RAWGQ  ((size_t)42598400)
#define B_RAWGK  ((size_t)42663936)
#define B_GQ     ((size_t)42729472)
#define B_GK     ((size_t)43253760)
#define B_POS    ((size_t)42729472)
#define B_LSEP   ((size_t)42754560)
#define B_LGR    ((size_t)42930176)
#define B_FLAG   ((size_t)42930688)

extern "C" void kernel_launch(void* const* d_in, const int* in_sizes, int n_in,
                              void* d_out, int out_size, void* d_ws, size_t ws_size,
                              hipStream_t stream) {
    (void)in_sizes; (void)n_in; (void)out_size;
    const void* feat_q = d_in[0];
    const void* feat_k = d_in[1];
    const void* Wg1 = d_in[2];  const void* bg1 = d_in[3];
    const void* Wg2 = d_in[4];  const void* bg2 = d_in[5];
    const void* Wd1 = d_in[6];  const void* bd1 = d_in[7];
    const void* Wd2 = d_in[8];  const void* bd2 = d_in[9];
    const void* mWg1 = d_in[10]; const void* mbg1 = d_in[11];
    const void* mWg2 = d_in[12]; const void* mbg2 = d_in[13];
    const void* mWd1 = d_in[14]; const void* mbd1 = d_in[15];
    const void* mWd2 = d_in[16]; const void* mbd2 = d_in[17];
    char* ws = (char*)d_ws;

    if (ws_size >= A_NEED) {
        // =================== BIG PATH ===================
        unsigned short* FQ    = (unsigned short*)(ws + A_FQ);
        unsigned short* FK    = (unsigned short*)(ws + A_FK);
        unsigned short* WD1T  = (unsigned short*)(ws + A_WD1T);
        unsigned short* MWD1T = (unsigned short*)(ws + A_MWD1T);
        unsigned short* WG1T  = (unsigned short*)(ws + A_WG1T);
        unsigned short* MWG1T = (unsigned short*)(ws + A_MWG1T);
        unsigned short* W2dq  = (unsigned short*)(ws + A_W2DQ);
        unsigned short* W2dk  = (unsigned short*)(ws + A_W2DK);
        unsigned short* W2gq  = (unsigned short*)(ws + A_W2GQ);
        unsigned short* W2gk  = (unsigned short*)(ws + A_W2GK);
        float* rawdq = (float*)(ws + A_RAWDQ);
        float* rawdk = (float*)(ws + A_RAWDK);
        float* rawgq = (float*)(ws + A_RAWGQ);
        float* rawgk = (float*)(ws + A_RAWGK);
        unsigned short* gq = (unsigned short*)(ws + A_GQ);
        unsigned short* gk = (unsigned short*)(ws + A_GK);
        unsigned short* qd = (unsigned short*)(ws + A_QD);
        unsigned short* kd = (unsigned short*)(ws + A_KD);
        unsigned short* mt = (unsigned short*)(ws + A_MT);
        float* pos  = (float*)(ws + A_POS);
        float* lsep = (float*)(ws + A_RAWDQ);   // rawdq region is dead after simmatch
        float* lgr  = (float*)(ws + A_LGR);
        int*   flag = (int*)(ws + A_FLAG);

        detect_kernel<<<1, 64, 0, stream>>>((const unsigned short*)feat_q, flag);
        convpool_kernel<<<dim3(4, 128, 2), 256, 0, stream>>>(feat_q, feat_k, FQ, FK, gq, gk, flag);
        transpose4v_kernel<<<dim3(32, 32, 4), 256, 0, stream>>>(
            Wd1, mWd1, Wg1, mWg1, WD1T, MWD1T, WG1T, MWG1T, 2048, 2048, flag);
        transpose4v_kernel<<<dim3(2, 32, 4), 256, 0, stream>>>(
            Wd2, mWd2, Wg2, mWg2, W2dq, W2dk, W2gq, W2gk, 2048, 128, flag);
        zero_kernel<<<1600, 256, 0, stream>>>(rawdq, 409600);
        mlp_mega_kernel<<<dim3(16, 50, 2), 256, 0, stream>>>(
            FQ, FK, gq, gk, WD1T, MWD1T, WG1T, MWG1T,
            W2dq, W2dk, W2gq, W2gk, bd1, mbd1, bg1, mbg1,
            rawdq, rawdk, rawgq, rawgk, flag);
        simmatch_kernel<<<dim3(128, 2), 256, 0, stream>>>(rawdq, rawdk, bd2, mbd2, qd, kd, mt, pos, flag);
        lse_kernel<<<dim3(49, NZSPLIT), 256, 0, stream>>>(qd, mt, lsep);
        lg_kernel<<<16, 128, 0, stream>>>(rawgq, rawgk, bg2, mbg2, lgr, flag);
        final_kernel<<<1, 256, 0, stream>>>(lsep, pos, lgr, (unsigned int*)d_out);
    } else {
        // =================== SMALL PATH ===================
        unsigned short* slotA = (unsigned short*)(ws + B_SLOTA);
        unsigned short* slotB = (unsigned short*)(ws + B_SLOTB);
        unsigned short* W2dq = (unsigned short*)(ws + B_W2DQ);
        unsigned short* W2dk = (unsigned short*)(ws + B_W2DK);
        unsigned short* W2gq = (unsigned short*)(ws + B_W2GQ);
        unsigned short* W2gk = (unsigned short*)(ws + B_W2GK);
        float* rawdq = (float*)(ws + B_RAWDQ);
        float* rawdk = (float*)(ws + B_RAWDK);
        float* rawgq = (float*)(ws + B_RAWGQ);
        float* rawgk = (float*)(ws + B_RAWGK);
        unsigned short* gq = (unsigned short*)(ws + B_GQ);
        unsigned short* gk = (unsigned short*)(ws + B_GK);
        unsigned short* qd = (unsigned short*)(ws + B_QD);
        unsigned short* kd = (unsigned short*)(ws + B_KD);
        unsigned short* mt = (unsigned short*)(ws + B_MT);
        float* pos  = (float*)(ws + B_POS);
        float* lsep = (float*)(ws + B_RAWDQ);   // rawdq region dead after simmatch
        float* lgr  = (float*)(ws + B_LGR);
        int*   flag = (int*)(ws + B_FLAG);

        detect_kernel<<<1, 64, 0, stream>>>((const unsigned short*)feat_q, flag);
        pool_kernel<<<dim3(8, 128, 2), 256, 0, stream>>>(feat_q, feat_k, gq, gk, flag);
        transpose2v_kernel<<<dim3(32, 32, 2), 256, 0, stream>>>(Wg1, mWg1, slotA, slotB, 2048, 2048, flag);
        transpose4v_kernel<<<dim3(2, 32, 4), 256, 0, stream>>>(
            Wd2, mWd2, Wg2, mWg2, W2dq, W2dk, W2gq, W2gk, 2048, 128, flag);
        zero_kernel<<<1600, 256, 0, stream>>>(rawdq, 409600);
        mlp_kernel<<<dim3(16, 1, 2), 256, 0, stream>>>(
            gq, gk, slotA, slotB, W2gq, W2gk, bg1, mbg1, rawgq, rawgk, flag);
        transpose2v_kernel<<<dim3(32, 32, 1), 256, 0, stream>>>(Wd1, Wd1, slotA, slotA, 2048, 2048, flag);
        convert_kernel<<<6272, 256, 0, stream>>>(feat_q, slotB, flag);
        mlp_kernel<<<dim3(16, 49, 1), 256, 0, stream>>>(
            slotB, slotB, slotA, slotA, W2dq, W2dq, bd1, bd1, rawdq, rawdq, flag);
        transpose2v_kernel<<<dim3(32, 32, 1), 256, 0, stream>>>(mWd1, mWd1, slotA, slotA, 2048, 2048, flag);
        convert_kernel<<<6272, 256, 0, stream>>>(feat_k, slotB, flag);
        mlp_kernel<<<dim3(16, 49, 1), 256, 0, stream>>>(
            slotB, slotB, slotA, slotA, W2dk, W2dk, mbd1, mbd1, rawdk, rawdk, flag);
        simmatch_kernel<<<dim3(128, 2), 256, 0, stream>>>(rawdq, rawdk, bd2, mbd2, qd, kd, mt, pos, flag);
        lse_kernel<<<dim3(49, NZSPLIT), 256, 0, stream>>>(qd, mt, lsep);
        lg_kernel<<<16, 128, 0, stream>>>(rawgq, rawgk, bg2, mbg2, lgr, flag);
        final_kernel<<<1, 256, 0, stream>>>(lsep, pos, lgr, (unsigned int*)d_out);
    }
}

// Round 9
// 514.598 us; speedup vs baseline: 2.0751x; 1.0333x over previous
//
#include <hip/hip_runtime.h>
#include <cstddef>

typedef __bf16 bf16x8 __attribute__((ext_vector_type(8)));
typedef float  f32x4  __attribute__((ext_vector_type(4)));
typedef float  f32x2  __attribute__((ext_vector_type(2)));
typedef unsigned short u16x8 __attribute__((ext_vector_type(8)));
typedef unsigned short u16x4 __attribute__((ext_vector_type(4)));
typedef unsigned short u16x2 __attribute__((ext_vector_type(2)));

__device__ __forceinline__ float b2f(unsigned short u) {
    union { unsigned int i; float f; } v; v.i = ((unsigned int)u) << 16; return v.f;
}
__device__ __forceinline__ unsigned short f2b(float f) {
    union { float f; unsigned int i; } v; v.f = f;
    unsigned int r = v.i + 0x7fffu + ((v.i >> 16) & 1u);
    return (unsigned short)(r >> 16);
}
__device__ __forceinline__ void gl_lds16(const void* g, void* l) {
    __builtin_amdgcn_global_load_lds((const __attribute__((address_space(1))) void*)g,
                                     (__attribute__((address_space(3))) void*)l,
                                     16, 0, 0);
}

// XCD-aware bijective block swizzle (m204 form).
__device__ __forceinline__ void xcd_swizzle(int& bx, int& by, int& bz) {
    unsigned int nx = gridDim.x, ny = gridDim.y;
    unsigned int n = nx * ny * gridDim.z;
    unsigned int lin = blockIdx.x + nx * (blockIdx.y + ny * blockIdx.z);
    unsigned int q = n >> 3, r = n & 7u;
    unsigned int xcd = lin & 7u, off = lin >> 3;
    unsigned int s = (xcd < r) ? (xcd * (q + 1u) + off)
                               : (r * (q + 1u) + (xcd - r) * q + off);
    bx = (int)(s % nx); s /= nx;
    by = (int)(s % ny);
    bz = (int)(s / ny);
}

// ------------------- input dtype detector -------------------
__global__ __launch_bounds__(64) void detect_kernel(const unsigned short* __restrict__ feat,
                                                    int* __restrict__ flag) {
    __shared__ int cnt;
    if (threadIdx.x == 0) cnt = 0;
    __syncthreads();
    int c = 0;
    for (int i = threadIdx.x; i < 256; i += 64) {
        float v = b2f(feat[i]);
        if (fabsf(v) > 100.0f) ++c;
    }
    atomicAdd(&cnt, c);
    __syncthreads();
    if (threadIdx.x == 0) *flag = (cnt > 16) ? 1 : 0;   // 1 => inputs are fp32
}

// ------------------- zero fill (small path) -------------------
__global__ __launch_bounds__(256) void zero_kernel(float* __restrict__ p, int n4) {
    int i = blockIdx.x * 256 + threadIdx.x;
    const f32x4 z = {0.f, 0.f, 0.f, 0.f};
    if (i < n4) ((f32x4*)p)[i] = z;
}

// ======================= BIG PATH: fused prep dispatch =======================
// convpool + 4x big transpose + 4x small transpose + zero-fill merged into ONE
// kernel: the four phases are mutually independent (disjoint outputs, input-only
// reads) but were 4 serialized dispatches -> launch+drain gaps and no BW overlap.
// Flattened grid: [0,512) convpool (2,128,2) | [512,4608) transpose 2048x2048
// (32,32,4) | [4608,4864) transpose 2048x128 (2,32,4) | [4864,6464) zero.
__global__ __launch_bounds__(256) void prep_kernel(
    const void* __restrict__ fq, const void* __restrict__ fk,
    unsigned short* __restrict__ FQ, unsigned short* __restrict__ FK,
    unsigned short* __restrict__ gq, unsigned short* __restrict__ gk,
    const void* __restrict__ Wd1, const void* __restrict__ mWd1,
    const void* __restrict__ Wg1, const void* __restrict__ mWg1,
    unsigned short* __restrict__ WD1T, unsigned short* __restrict__ MWD1T,
    unsigned short* __restrict__ WG1T, unsigned short* __restrict__ MWG1T,
    const void* __restrict__ Wd2, const void* __restrict__ mWd2,
    const void* __restrict__ Wg2, const void* __restrict__ mWg2,
    unsigned short* __restrict__ W2dq, unsigned short* __restrict__ W2dk,
    unsigned short* __restrict__ W2gq, unsigned short* __restrict__ W2gk,
    float* __restrict__ zeros, const int* __restrict__ flagp)
{
    __shared__ unsigned short tile[64 * 72];
    int fl = *flagp;
    unsigned int bid = blockIdx.x;
    int t = threadIdx.x;

    if (bid < 512) {
        // ---- convpool: convert feat->bf16 + global average pool ----
        // decode dim3(2,128,2); thread owns 4 consecutive c (f32x4 = 16B/lane)
        int x = bid & 1;
        int b = (bid >> 1) & 127;
        int z = (int)(bid >> 8);
        const void* src = z ? fk : fq;
        unsigned short* dst = z ? FK : FQ;
        unsigned short* g   = z ? gk : gq;
        int c0 = x * 1024 + t * 4;
        float s0 = 0.f, s1 = 0.f, s2 = 0.f, s3 = 0.f;
        if (fl) {
            const float* sf = (const float*)src;
            for (int p = 0; p < 49; ++p) {
                size_t idx = ((size_t)b * 49 + p) * 2048 + c0;
                f32x4 v = *(const f32x4*)(sf + idx);
                u16x4 o; o[0]=f2b(v[0]); o[1]=f2b(v[1]); o[2]=f2b(v[2]); o[3]=f2b(v[3]);
                s0 += v[0]; s1 += v[1]; s2 += v[2]; s3 += v[3];
                *(u16x4*)(dst + idx) = o;
            }
        } else {
            const unsigned short* su = (const unsigned short*)src;
            for (int p = 0; p < 49; ++p) {
                size_t idx = ((size_t)b * 49 + p) * 2048 + c0;
                u16x4 o = *(const u16x4*)(su + idx);
                s0 += b2f(o[0]); s1 += b2f(o[1]); s2 += b2f(o[2]); s3 += b2f(o[3]);
                *(u16x4*)(dst + idx) = o;
            }
        }
        u16x4 gm;
        gm[0] = f2b(s0 * (1.0f / 49.0f)); gm[1] = f2b(s1 * (1.0f / 49.0f));
        gm[2] = f2b(s2 * (1.0f / 49.0f)); gm[3] = f2b(s3 * (1.0f / 49.0f));
        *(u16x4*)(g + (size_t)b * 2048 + c0) = gm;
    } else if (bid < 4608 || (bid < 4864)) {
        // ---- transpose+convert (64x64 tiles) — big (2048x2048) or small (2048x128) ----
        const void* in; unsigned short* out; int rows, cols, bx, by;
        if (bid < 4608) {
            unsigned int l = bid - 512;
            int x = l & 31, y = (l >> 5) & 31, z = (int)(l >> 10);
            in  = (z == 0) ? Wd1 : (z == 1) ? mWd1 : (z == 2) ? Wg1 : mWg1;
            out = (z == 0) ? WD1T : (z == 1) ? MWD1T : (z == 2) ? WG1T : MWG1T;
            rows = 2048; cols = 2048; bx = x * 64; by = y * 64;
        } else {
            unsigned int l = bid - 4608;
            int x = l & 1, y = (l >> 1) & 31, z = (int)(l >> 6);
            in  = (z == 0) ? Wd2 : (z == 1) ? mWd2 : (z == 2) ? Wg2 : mWg2;
            out = (z == 0) ? W2dq : (z == 1) ? W2dk : (z == 2) ? W2gq : W2gk;
            rows = 2048; cols = 128; bx = x * 64; by = y * 64;
        }
        int tr = t >> 3;
        int tc = (t & 7) * 8;
        #pragma unroll
        for (int h = 0; h < 2; ++h) {
            int r = tr + h * 32;
            if (fl) {
                const float* inf = (const float*)in + (size_t)(by + r) * cols + bx + tc;
                f32x4 v0 = *(const f32x4*)inf;
                f32x4 v1 = *(const f32x4*)(inf + 4);
                u16x8 o;
                o[0]=f2b(v0[0]); o[1]=f2b(v0[1]); o[2]=f2b(v0[2]); o[3]=f2b(v0[3]);
                o[4]=f2b(v1[0]); o[5]=f2b(v1[1]); o[6]=f2b(v1[2]); o[7]=f2b(v1[3]);
                *(u16x8*)(tile + r * 72 + tc) = o;
            } else {
                const unsigned short* inu = (const unsigned short*)in + (size_t)(by + r) * cols + bx + tc;
                *(u16x8*)(tile + r * 72 + tc) = *(const u16x8*)inu;
            }
        }
        __syncthreads();
        #pragma unroll
        for (int h = 0; h < 2; ++h) {
            int oc = tr + h * 32;
            u16x8 v;
            #pragma unroll
            for (int j = 0; j < 8; ++j) v[j] = tile[(tc + j) * 72 + oc];
            *(u16x8*)(out + (size_t)(bx + oc) * rows + by + tc) = v;
        }
    } else {
        // ---- zero fill: 1600 blocks x 256 x 16B = 6.55 MB (rawdq..rawgk) ----
        unsigned int l = bid - 4864;
        const f32x4 z4 = {0.f, 0.f, 0.f, 0.f};
        ((f32x4*)zeros)[(size_t)l * 256 + t] = z4;
    }
}

// ------------------- SMALL PATH: convert feat -> bf16 -------------------
__global__ __launch_bounds__(256) void convert_kernel(const void* __restrict__ in,
                                                      unsigned short* __restrict__ out,
                                                      const int* __restrict__ flagp) {
    int fl = *flagp;
    size_t i = ((size_t)blockIdx.x * 256 + threadIdx.x) * 8;
    if (fl) {
        const float* inf = (const float*)in;
        f32x4 v0 = *(const f32x4*)(inf + i);
        f32x4 v1 = *(const f32x4*)(inf + i + 4);
        u16x8 o;
        o[0]=f2b(v0[0]); o[1]=f2b(v0[1]); o[2]=f2b(v0[2]); o[3]=f2b(v0[3]);
        o[4]=f2b(v1[0]); o[5]=f2b(v1[1]); o[6]=f2b(v1[2]); o[7]=f2b(v1[3]);
        *(u16x8*)(out + i) = o;
    } else {
        *(u16x8*)(out + i) = *(const u16x8*)((const unsigned short*)in + i);
    }
}

// ------------------- SMALL PATH: global average pool -------------------
__global__ __launch_bounds__(256) void pool_kernel(const void* __restrict__ fq,
                                                   const void* __restrict__ fk,
                                                   unsigned short* __restrict__ gq,
                                                   unsigned short* __restrict__ gk,
                                                   const int* __restrict__ flagp) {
    int fl = *flagp;
    int c = blockIdx.x * 256 + threadIdx.x;
    int b = blockIdx.y;
    const void* src = blockIdx.z ? fk : fq;
    unsigned short* dst = blockIdx.z ? gk : gq;
    size_t base = (size_t)b * 49 * 2048 + c;
    float s = 0.f;
    if (fl) {
        const float* sf = (const float*)src;
        #pragma unroll
        for (int p = 0; p < 49; ++p) s += sf[base + (size_t)p * 2048];
    } else {
        const unsigned short* su = (const unsigned short*)src;
        #pragma unroll
        for (int p = 0; p < 49; ++p) s += b2f(su[base + (size_t)p * 2048]);
    }
    dst[(size_t)b * 2048 + c] = f2b(s * (1.0f / 49.0f));
}

// ------------------- 2-way vectorized transpose+convert (64x64 tiles) -------------------
__global__ __launch_bounds__(256) void transpose2v_kernel(
    const void* __restrict__ s0, const void* __restrict__ s1,
    unsigned short* __restrict__ d0, unsigned short* __restrict__ d1,
    int rows, int cols, const int* __restrict__ flagp) {
    int fl = *flagp;
    int z = blockIdx.z;
    const void* in = z ? s1 : s0;
    unsigned short* out = z ? d1 : d0;
    __shared__ unsigned short tile[64 * 72];
    int bx = blockIdx.x * 64, by = blockIdx.y * 64;
    int tr = threadIdx.x >> 3;
    int tc = (threadIdx.x & 7) * 8;
    #pragma unroll
    for (int h = 0; h < 2; ++h) {
        int r = tr + h * 32;
        if (fl) {
            const float* inf = (const float*)in + (size_t)(by + r) * cols + bx + tc;
            f32x4 v0 = *(const f32x4*)inf;
            f32x4 v1 = *(const f32x4*)(inf + 4);
            u16x8 o;
            o[0]=f2b(v0[0]); o[1]=f2b(v0[1]); o[2]=f2b(v0[2]); o[3]=f2b(v0[3]);
            o[4]=f2b(v1[0]); o[5]=f2b(v1[1]); o[6]=f2b(v1[2]); o[7]=f2b(v1[3]);
            *(u16x8*)(tile + r * 72 + tc) = o;
        } else {
            const unsigned short* inu = (const unsigned short*)in + (size_t)(by + r) * cols + bx + tc;
            *(u16x8*)(tile + r * 72 + tc) = *(const u16x8*)inu;
        }
    }
    __syncthreads();
    #pragma unroll
    for (int h = 0; h < 2; ++h) {
        int oc = tr + h * 32;
        u16x8 v;
        #pragma unroll
        for (int j = 0; j < 8; ++j) v[j] = tile[(tc + j) * 72 + oc];
        *(u16x8*)(out + (size_t)(bx + oc) * rows + by + tc) = v;
    }
}

// ------------------- 4-way vectorized transpose+convert (small path) -------------------
__global__ __launch_bounds__(256) void transpose4v_kernel(
    const void* __restrict__ s0, const void* __restrict__ s1,
    const void* __restrict__ s2, const void* __restrict__ s3,
    unsigned short* __restrict__ d0, unsigned short* __restrict__ d1,
    unsigned short* __restrict__ d2, unsigned short* __restrict__ d3,
    int rows, int cols, const int* __restrict__ flagp) {
    int fl = *flagp;
    int z = blockIdx.z;
    const void* in = (z == 0) ? s0 : (z == 1) ? s1 : (z == 2) ? s2 : s3;
    unsigned short* out = (z == 0) ? d0 : (z == 1) ? d1 : (z == 2) ? d2 : d3;
    __shared__ unsigned short tile[64 * 72];
    int bx = blockIdx.x * 64, by = blockIdx.y * 64;
    int tr = threadIdx.x >> 3;
    int tc = (threadIdx.x & 7) * 8;
    #pragma unroll
    for (int h = 0; h < 2; ++h) {
        int r = tr + h * 32;
        if (fl) {
            const float* inf = (const float*)in + (size_t)(by + r) * cols + bx + tc;
            f32x4 v0 = *(const f32x4*)inf;
            f32x4 v1 = *(const f32x4*)(inf + 4);
            u16x8 o;
            o[0]=f2b(v0[0]); o[1]=f2b(v0[1]); o[2]=f2b(v0[2]); o[3]=f2b(v0[3]);
            o[4]=f2b(v1[0]); o[5]=f2b(v1[1]); o[6]=f2b(v1[2]); o[7]=f2b(v1[3]);
            *(u16x8*)(tile + r * 72 + tc) = o;
        } else {
            const unsigned short* inu = (const unsigned short*)in + (size_t)(by + r) * cols + bx + tc;
            *(u16x8*)(tile + r * 72 + tc) = *(const u16x8*)inu;
        }
    }
    __syncthreads();
    #pragma unroll
    for (int h = 0; h < 2; ++h) {
        int oc = tr + h * 32;
        u16x8 v;
        #pragma unroll
        for (int j = 0; j < 8; ++j) v[j] = tile[(tc + j) * 72 + oc];
        *(u16x8*)(out + (size_t)(bx + oc) * rows + by + tc) = v;
    }
}

// ======================= MLP core (shared device function) =======================
// K-loop: double-buffered with COUNTED vmcnt (T4) + raw barriers + setprio (T5).
// NOTE (R4-R7): the 256^2/512-thread port is blocked by the toolchain pinning
// 512-thread kernels to 128 VGPRs (acc spills; ~700us). This 256-thread form
// (VGPR 108, no spill) is the verified optimum.
__device__ __forceinline__ void mlp_body(
    const unsigned short* __restrict__ A, const unsigned short* __restrict__ Bt,
    const unsigned short* __restrict__ W2, const void* __restrict__ b1,
    float* __restrict__ outp, size_t m0, size_t n0, int fl)
{
    const int K = 2048;
    __shared__ unsigned short smem[32768];   // 64 KB
    unsigned short* As0 = smem;
    unsigned short* Bs0 = smem + 8192;
    unsigned short* As1 = smem + 16384;
    unsigned short* Bs1 = smem + 24576;
    unsigned short* W2s = smem;              // phase 2 aliases buf0 A
    unsigned short* Hs  = smem + 8192;       // phase 2: 128 x 72

    int tid  = threadIdx.x;
    int lane = tid & 63;
    int w    = tid >> 6;
    int wm = w & 1, wn = w >> 1;
    int quad = lane >> 4, l16 = lane & 15;
    int lrow = lane >> 3;
    int kc   = (lane & 7) ^ lrow;

    const unsigned short* gA[4];
    const unsigned short* gB[4];
    int off[4];
    #pragma unroll
    for (int c = 0; c < 4; ++c) {
        int row = w * 32 + c * 8 + lrow;
        gA[c] = A  + (m0 + row) * (size_t)K + kc * 8;
        gB[c] = Bt + (n0 + row) * (size_t)K + kc * 8;
        off[c] = w * 2048 + c * 512;
    }

    const f32x4 zero4 = {0.f, 0.f, 0.f, 0.f};
    f32x4 acc[4][4];
    #pragma unroll
    for (int i = 0; i < 4; ++i)
        #pragma unroll
        for (int j = 0; j < 4; ++j) acc[i][j] = zero4;

    int swz = l16 & 7;

#define STAGE(Ad, Bd) do { \
    _Pragma("unroll") \
    for (int c = 0; c < 4; ++c) { gl_lds16(gA[c], (Ad) + off[c]); gA[c] += 64; } \
    _Pragma("unroll") \
    for (int c = 0; c < 4; ++c) { gl_lds16(gB[c], (Bd) + off[c]); gB[c] += 64; } \
} while (0)

#define CSTEP(Asrc, Bsrc) do { \
    _Pragma("unroll") \
    for (int k0 = 0; k0 < 64; k0 += 32) { \
        bf16x8 af[4], bfr[4]; \
        _Pragma("unroll") \
        for (int mt = 0; mt < 4; ++mt) { \
            int row = wm * 64 + mt * 16 + l16; \
            int sc  = (((k0 >> 3) + quad) ^ swz) << 3; \
            af[mt] = *(const bf16x8*)((Asrc) + row * 64 + sc); \
        } \
        _Pragma("unroll") \
        for (int nt = 0; nt < 4; ++nt) { \
            int row = wn * 64 + nt * 16 + l16; \
            int sc  = (((k0 >> 3) + quad) ^ swz) << 3; \
            bfr[nt] = *(const bf16x8*)((Bsrc) + row * 64 + sc); \
        } \
        __builtin_amdgcn_s_setprio(1); \
        _Pragma("unroll") \
        for (int mt = 0; mt < 4; ++mt) \
            _Pragma("unroll") \
            for (int nt = 0; nt < 4; ++nt) \
                acc[mt][nt] = __builtin_amdgcn_mfma_f32_16x16x32_bf16(af[mt], bfr[nt], acc[mt][nt], 0, 0, 0); \
        __builtin_amdgcn_s_setprio(0); \
    } \
} while (0)

    // prologue: stage K[0:64) into buf0 (8 loads in flight per wave)
    STAGE(As0, Bs0);
    #pragma unroll 1
    for (int kb2 = 0; kb2 < 16; ++kb2) {
        // ---- half A: prefetch buf1, compute buf0 ----
        STAGE(As1, Bs1);                                    // 16 in flight
        asm volatile("s_waitcnt vmcnt(8)" ::: "memory");    // buf0 ready (this wave)
        __builtin_amdgcn_s_barrier();                       // buf0 ready (all waves)
        __builtin_amdgcn_sched_barrier(0);
        CSTEP(As0, Bs0);
        asm volatile("s_waitcnt lgkmcnt(0)" ::: "memory");
        __builtin_amdgcn_sched_barrier(0);
        __builtin_amdgcn_s_barrier();                       // WAR: all done reading buf0
        // ---- half B: prefetch buf0, compute buf1 ----
        if (kb2 < 15) {
            STAGE(As0, Bs0);                                // 16 in flight
            asm volatile("s_waitcnt vmcnt(8)" ::: "memory");// buf1 ready
        } else {
            asm volatile("s_waitcnt vmcnt(0)" ::: "memory");// drain tail
        }
        __builtin_amdgcn_s_barrier();
        __builtin_amdgcn_sched_barrier(0);
        CSTEP(As1, Bs1);
        asm volatile("s_waitcnt lgkmcnt(0)" ::: "memory");
        __builtin_amdgcn_sched_barrier(0);
        __builtin_amdgcn_s_barrier();                       // WAR: all done reading buf1
    }
#undef STAGE
#undef CSTEP

    float b1v[4];
    #pragma unroll
    for (int nt = 0; nt < 4; ++nt) {
        int col = (int)n0 + wn * 64 + nt * 16 + l16;
        b1v[nt] = fl ? ((const float*)b1)[col] : b2f(((const unsigned short*)b1)[col]);
    }

    f32x4 acc2[4][4];
    #pragma unroll
    for (int i = 0; i < 4; ++i)
        #pragma unroll
        for (int j = 0; j < 4; ++j) acc2[i][j] = zero4;

    #pragma unroll
    for (int hf = 0; hf < 2; ++hf) {
        __syncthreads();
        if (wn == hf) {
            #pragma unroll
            for (int mt = 0; mt < 4; ++mt)
                #pragma unroll
                for (int nt = 0; nt < 4; ++nt)
                    #pragma unroll
                    for (int r = 0; r < 4; ++r) {
                        float v = fmaxf(acc[mt][nt][r] + b1v[nt], 0.f);
                        Hs[(wm * 64 + mt * 16 + quad * 4 + r) * 72 + nt * 16 + l16] = f2b(v);
                    }
        } else {
            #pragma unroll
            for (int c = 0; c < 8; ++c) {
                const unsigned short* g = W2 + (size_t)(wm * 64 + c * 8 + lrow) * 2048
                                          + n0 + hf * 64 + kc * 8;
                gl_lds16(g, W2s + wm * 4096 + c * 512);
            }
        }
        __syncthreads();
        #pragma unroll
        for (int k0 = 0; k0 < 64; k0 += 32) {
            bf16x8 ha[4], wb[4];
            #pragma unroll
            for (int mt = 0; mt < 4; ++mt)
                ha[mt] = *(const bf16x8*)(Hs + (wm * 64 + mt * 16 + l16) * 72 + k0 + quad * 8);
            #pragma unroll
            for (int et = 0; et < 4; ++et) {
                int row = wn * 64 + et * 16 + l16;
                int sc  = (((k0 >> 3) + quad) ^ swz) << 3;
                wb[et] = *(const bf16x8*)(W2s + row * 64 + sc);
            }
            #pragma unroll
            for (int mt = 0; mt < 4; ++mt)
                #pragma unroll
                for (int et = 0; et < 4; ++et)
                    acc2[mt][et] = __builtin_amdgcn_mfma_f32_16x16x32_bf16(ha[mt], wb[et], acc2[mt][et], 0, 0, 0);
        }
    }

    #pragma unroll
    for (int et = 0; et < 4; ++et) {
        int col = wn * 64 + et * 16 + l16;
        #pragma unroll
        for (int mt = 0; mt < 4; ++mt)
            #pragma unroll
            for (int r = 0; r < 4; ++r) {
                size_t row = m0 + wm * 64 + mt * 16 + quad * 4 + r;
                atomicAdd(&outp[row * 128 + col], acc2[mt][et][r]);
            }
    }
}

// ---- BIG PATH: mega mlp, grid (16, 50, 2): y<49 dense strips, y=49 global head ----
__global__ __launch_bounds__(256) void mlp_mega_kernel(
    const unsigned short* __restrict__ FQ, const unsigned short* __restrict__ FK,
    const unsigned short* __restrict__ gq, const unsigned short* __restrict__ gk,
    const unsigned short* __restrict__ WD1T, const unsigned short* __restrict__ MWD1T,
    const unsigned short* __restrict__ WG1T, const unsigned short* __restrict__ MWG1T,
    const unsigned short* __restrict__ W2dq, const unsigned short* __restrict__ W2dk,
    const unsigned short* __restrict__ W2gq, const unsigned short* __restrict__ W2gk,
    const void* __restrict__ bd1, const void* __restrict__ mbd1,
    const void* __restrict__ bg1, const void* __restrict__ mbg1,
    float* __restrict__ rawdq, float* __restrict__ rawdk,
    float* __restrict__ rawgq, float* __restrict__ rawgk,
    const int* __restrict__ flagp)
{
    int fl = *flagp;
    int bx, by, bz;
    xcd_swizzle(bx, by, bz);
    int z = bz;
    int isg = (by == 49);
    const unsigned short *A, *Bt, *W2; const void* b1; float* outp;
    if (!isg) {
        A = z ? FK : FQ;  Bt = z ? MWD1T : WD1T;  W2 = z ? W2dk : W2dq;
        b1 = z ? mbd1 : bd1;  outp = z ? rawdk : rawdq;
    } else {
        A = z ? gk : gq;  Bt = z ? MWG1T : WG1T;  W2 = z ? W2gk : W2gq;
        b1 = z ? mbg1 : bg1;  outp = z ? rawgk : rawgq;
    }
    size_t m0 = isg ? 0 : (size_t)by * 128;
    size_t n0 = (size_t)bx * 128;
    mlp_body(A, Bt, W2, b1, outp, m0, n0, fl);
}

// ---- SMALL PATH: pair mlp (z selects pointer pair) ----
__global__ __launch_bounds__(256) void mlp_kernel(
    const unsigned short* __restrict__ A0, const unsigned short* __restrict__ A1,
    const unsigned short* __restrict__ Bt0, const unsigned short* __restrict__ Bt1,
    const unsigned short* __restrict__ W20, const unsigned short* __restrict__ W21,
    const void* __restrict__ b10, const void* __restrict__ b11,
    float* __restrict__ out0, float* __restrict__ out1,
    const int* __restrict__ flagp)
{
    int fl = *flagp;
    int bx, by, bz;
    xcd_swizzle(bx, by, bz);
    int z  = bz;
    mlp_body(z ? A1 : A0, z ? Bt1 : Bt0, z ? W21 : W20, z ? b11 : b10,
             z ? out1 : out0, (size_t)by * 128, (size_t)bx * 128, fl);
}

// ---- fused dense: bias + l2norm (writes qd/kd) + sim 49x49 + argmax + matched + pos ----
// Grid (128, 2): y splits the 49 query rows 25/24 across two blocks.
__global__ __launch_bounds__(256) void simmatch_kernel(
    const float* __restrict__ rawdq, const float* __restrict__ rawdk,
    const void* __restrict__ bd2, const void* __restrict__ mbd2,
    unsigned short* __restrict__ qd, unsigned short* __restrict__ kd,
    unsigned short* __restrict__ matched, float* __restrict__ pos,
    const int* __restrict__ flagp) {
    int fl = *flagp;
    __shared__ float f1s[49 * 128];
    __shared__ float f2s[49 * 128];
    int b = blockIdx.x;
    int half = blockIdx.y;
    int t = threadIdx.x;
    size_t base = (size_t)b * 49 * 128;

    int rr = t >> 2, jq = t & 3;
    if (rr < 49) {
        #pragma unroll
        for (int br = 0; br < 2; ++br) {
            const float* raw = br ? rawdk : rawdq;
            const void* bias = br ? mbd2 : bd2;
            unsigned short* outg = br ? kd : qd;
            float* fs = br ? f2s : f1s;
            size_t idx = base + (size_t)rr * 128 + jq * 32;
            float x[32];
            float ss = 0.f;
            #pragma unroll
            for (int c = 0; c < 32; ++c) {
                float bv = fl ? ((const float*)bias)[jq * 32 + c]
                              : b2f(((const unsigned short*)bias)[jq * 32 + c]);
                x[c] = raw[idx + c] + bv;
                ss += x[c] * x[c];
            }
            ss += __shfl_xor(ss, 1); ss += __shfl_xor(ss, 2);
            float rs = rsqrtf(fmaxf(ss, 1e-12f));
            #pragma unroll
            for (int c = 0; c < 32; ++c) {
                unsigned short us = f2b(x[c] * rs);
                if (half == 0) outg[idx + c] = us;
                fs[rr * 128 + jq * 32 + c] = b2f(us);
            }
        }
    }
    __syncthreads();

    int i0 = t >> 2, q4 = t & 3;
    int i = half * 25 + i0;
    int ilim = half ? 24 : 25;
    if (i0 < ilim) {
        int mlo = q4 * 13;
        int mhi = mlo + 13; if (mhi > 49) mhi = 49;
        float best = -1e30f; int bi = 1 << 20;
        const f32x4* va = (const f32x4*)(f1s + i * 128);
        for (int m = mlo; m < mhi; ++m) {
            const f32x4* vb = (const f32x4*)(f2s + m * 128);
            float d = 0.f;
            #pragma unroll
            for (int j = 0; j < 32; ++j) {
                f32x4 a = va[j], bb = vb[j];
                d += a[0]*bb[0] + a[1]*bb[1] + a[2]*bb[2] + a[3]*bb[3];
            }
            if (d > best) { best = d; bi = m; }
        }
        #pragma unroll
        for (int off = 1; off < 4; off <<= 1) {
            float ov = __shfl_xor(best, off);
            int   oi = __shfl_xor(bi, off);
            if (ov > best || (ov == best && oi < bi)) { best = ov; bi = oi; }
        }
        if (q4 == 0) pos[b * 49 + i] = best * 5.0f;
        for (int j = q4 * 32; j < q4 * 32 + 32; ++j)
            matched[base + (size_t)i * 128 + j] = f2b(f2s[bi * 128 + j]);
    }
}

// ------------------- fused dense InfoNCE sum-of-exp, col-split x14 -------------------
#define KS 136
#define NZSPLIT 14
__global__ __launch_bounds__(256) void lse_kernel(const unsigned short* __restrict__ qd,
                                                  const unsigned short* __restrict__ matched,
                                                  float* __restrict__ lsep) {
    __shared__ unsigned short As[128 * KS];
    __shared__ unsigned short Bs[64 * KS];
    __shared__ float rsum[128];
    int tid  = threadIdx.x;
    int lane = tid & 63, wave = tid >> 6;
    int wm = wave & 1, wn = wave >> 1;
    int quad = lane >> 4, l16 = lane & 15;
    size_t m0 = (size_t)blockIdx.x * 128;
    int z = blockIdx.y;

    #pragma unroll
    for (int i = 0; i < 8; ++i) {
        int l = tid + 256 * i;
        int row = l >> 4, ko = (l & 15) << 3;
        u16x8 v = *(const u16x8*)(qd + (m0 + row) * 128 + ko);
        *(u16x8*)(As + row * KS + ko) = v;
    }
    if (tid < 128) rsum[tid] = 0.f;

    float rs[4][4];
    #pragma unroll
    for (int mt = 0; mt < 4; ++mt)
        #pragma unroll
        for (int r = 0; r < 4; ++r) rs[mt][r] = 0.f;

    const f32x4 zero4 = {0.f, 0.f, 0.f, 0.f};
    int nlo = z * 448, nhi = nlo + 448;
    for (int n0 = nlo; n0 < nhi; n0 += 64) {
        __syncthreads();
        #pragma unroll
        for (int i = 0; i < 4; ++i) {
            int l = tid + 256 * i;
            int row = l >> 4, ko = (l & 15) << 3;
            u16x8 v = *(const u16x8*)(matched + (size_t)(n0 + row) * 128 + ko);
            *(u16x8*)(Bs + row * KS + ko) = v;
        }
        __syncthreads();
        f32x4 acc[4][2];
        #pragma unroll
        for (int mt = 0; mt < 4; ++mt) { acc[mt][0] = zero4; acc[mt][1] = zero4; }
        #pragma unroll
        for (int k0 = 0; k0 < 128; k0 += 32) {
            bf16x8 af[4], bfr[2];
            #pragma unroll
            for (int mt = 0; mt < 4; ++mt)
                af[mt] = *(const bf16x8*)(As + (wm * 64 + mt * 16 + l16) * KS + k0 + quad * 8);
            #pragma unroll
            for (int nt = 0; nt < 2; ++nt)
                bfr[nt] = *(const bf16x8*)(Bs + (wn * 32 + nt * 16 + l16) * KS + k0 + quad * 8);
            #pragma unroll
            for (int mt = 0; mt < 4; ++mt)
                #pragma unroll
                for (int nt = 0; nt < 2; ++nt)
                    acc[mt][nt] = __builtin_amdgcn_mfma_f32_16x16x32_bf16(af[mt], bfr[nt], acc[mt][nt], 0, 0, 0);
        }
        #pragma unroll
        for (int mt = 0; mt < 4; ++mt)
            #pragma unroll
            for (int r = 0; r < 4; ++r)
                rs[mt][r] += __expf(acc[mt][0][r] * 5.0f) + __expf(acc[mt][1][r] * 5.0f);
    }
    #pragma unroll
    for (int mt = 0; mt < 4; ++mt)
        #pragma unroll
        for (int r = 0; r < 4; ++r) {
            float v = rs[mt][r];
            v += __shfl_xor(v, 1); v += __shfl_xor(v, 2);
            v += __shfl_xor(v, 4); v += __shfl_xor(v, 8);
            if (l16 == 0) atomicAdd(&rsum[wm * 64 + mt * 16 + quad * 4 + r], v);
        }
    __syncthreads();
    if (tid < 128) lsep[(size_t)z * 6272 + m0 + tid] = rsum[tid];
}

// ---- fused global: bias + l2norm (on the fly) + InfoNCE row term ----
__global__ __launch_bounds__(128) void lg_kernel(const float* __restrict__ rawgq,
                                                 const float* __restrict__ rawgk,
                                                 const void* __restrict__ bg2,
                                                 const void* __restrict__ mbg2,
                                                 float* __restrict__ lgrow,
                                                 const int* __restrict__ flagp) {
    int fl = *flagp;
    __shared__ float ksf[128 * 128];
    __shared__ float qsf[8 * 128];
    int t = threadIdx.x;
    int rbase = blockIdx.x * 8;
    {
        const float* rk = rawgk + (size_t)t * 128;
        float ss = 0.f;
        for (int c = 0; c < 128; ++c) {
            float bv = fl ? ((const float*)mbg2)[c] : b2f(((const unsigned short*)mbg2)[c]);
            float xx = rk[c] + bv;
            ss += xx * xx;
        }
        float rsv = rsqrtf(fmaxf(ss, 1e-12f));
        for (int c = 0; c < 128; ++c) {
            float bv = fl ? ((const float*)mbg2)[c] : b2f(((const unsigned short*)mbg2)[c]);
            ksf[t * 128 + c] = b2f(f2b((rk[c] + bv) * rsv));
        }
    }
    if (t < 8) {
        const float* rq = rawgq + (size_t)(rbase + t) * 128;
        float ss = 0.f;
        for (int c = 0; c < 128; ++c) {
            float bv = fl ? ((const float*)bg2)[c] : b2f(((const unsigned short*)bg2)[c]);
            float xx = rq[c] + bv;
            ss += xx * xx;
        }
        float rsv = rsqrtf(fmaxf(ss, 1e-12f));
        for (int c = 0; c < 128; ++c) {
            float bv = fl ? ((const float*)bg2)[c] : b2f(((const unsigned short*)bg2)[c]);
            qsf[t * 128 + c] = b2f(f2b((rq[c] + bv) * rsv));
        }
    }
    __syncthreads();
    int rl = t >> 4, jg = t & 15;
    int row = rbase + rl;
    float se = 0.f, diag = 0.f;
    for (int jj = 0; jj < 8; ++jj) {
        int j = jg * 8 + jj;
        float d = 0.f;
        #pragma unroll 8
        for (int c = 0; c < 128; ++c) d += qsf[rl * 128 + c] * ksf[j * 128 + c];
        d *= 5.0f;
        se += __expf(d);
        if (j == row) diag = d;
    }
    #pragma unroll
    for (int off = 1; off < 16; off <<= 1) { se += __shfl_xor(se, off); diag += __shfl_xor(diag, off); }
    if (jg == 0) lgrow[row] = logf(se) - diag;
}

// ------------------- final combine, dtype-hedged output -------------------
__global__ __launch_bounds__(256) void final_kernel(const float* __restrict__ lsep,
                                                    const float* __restrict__ pos,
                                                    const float* __restrict__ lgrow,
                                                    unsigned int* __restrict__ out) {
    int t = threadIdx.x;
    float s = 0.f;
    for (int i = t; i < 6272; i += 256) {
        float se = 0.f;
        #pragma unroll
        for (int zz = 0; zz < NZSPLIT; ++zz) se += lsep[zz * 6272 + i];
        s += logf(se) - pos[i];
    }
    float g = (t < 128) ? lgrow[t] : 0.f;
    #pragma unroll
    for (int off = 32; off >= 1; off >>= 1) { s += __shfl_xor(s, off); g += __shfl_xor(g, off); }
    __shared__ float p8[8];
    if ((t & 63) == 0) { p8[t >> 6] = s; p8[4 + (t >> 6)] = g; }
    __syncthreads();
    if (t == 0) {
        float ld  = (p8[0] + p8[1] + p8[2] + p8[3]) * (1.0f / 6272.0f);
        float lg  = (p8[4] + p8[5] + p8[6] + p8[7]) * (1.0f / 128.0f);
        float total = 0.5f * lg + 0.5f * ld;
        unsigned int L = f2b(total);
        union { float f; unsigned int u; } tb; tb.f = total;
        unsigned int base = (tb.u & 0xFFFF0000u) | L;
        unsigned int bu = base; float be = 1e30f;
        #pragma unroll
        for (int d = -1; d <= 1; ++d) {
            unsigned int c = base + ((unsigned int)d << 16);
            union { unsigned int u; float f; } cv; cv.u = c;
            float e = fabsf(cv.f - total);
            if (e < be) { be = e; bu = c; }
        }
        out[0] = bu;
    }
}

// ------------------- BIG layout (needs 99,652,608 B) -------------------
#define A_FQ     ((size_t)0)
#define A_FK     ((size_t)25690112)
#define A_WD1T   ((size_t)51380224)
#define A_MWD1T  ((size_t)59768832)
#define A_WG1T   ((size_t)68157440)
#define A_MWG1T  ((size_t)76546048)
#define A_W2DQ   ((size_t)84934656)
#define A_W2DK   ((size_t)85458944)
#define A_W2GQ   ((size_t)85983232)
#define A_W2GK   ((size_t)86507520)
#define A_RAWDQ  ((size_t)87031808)
#define A_RAWDK  ((size_t)90243072)
#define A_RAWGQ  ((size_t)93454336)
#define A_RAWGK  ((size_t)93519872)
#define A_GQ     ((size_t)93585408)
#define A_GK     ((size_t)94109696)
#define A_QD     ((size_t)94633984)
#define A_KD     ((size_t)96239616)
#define A_MT     ((size_t)97845248)
#define A_POS    ((size_t)99450880)
#define A_LSEP   ((size_t)99475968)
#define A_LGR    ((size_t)99651584)
#define A_FLAG   ((size_t)99652096)
#define A_NEED   ((size_t)99652608)
// lsep (14 slices x 6272 f32 = 343 KB) lives in the rawdq region (dead after simmatch).

// ------------------- SMALL layout (peak 43.78 MB) -------------------
#define B_SLOTA  ((size_t)0)
#define B_QD     ((size_t)0)
#define B_KD     ((size_t)1605632)
#define B_MT     ((size_t)3211264)
#define B_SLOTB  ((size_t)8388608)
#define B_W2DQ   ((size_t)34078720)
#define B_W2DK   ((size_t)34603008)
#define B_W2GQ   ((size_t)35127296)
#define B_W2GK   ((size_t)35651584)
#define B_RAWDQ  ((size_t)36175872)
#define B_RAWDK  ((size_t)39387136)
#define B_RAWGQ  ((size_t)42598400)
#define B_RAWGK  ((size_t)42663936)
#define B_GQ     ((size_t)42729472)
#define B_GK     ((size_t)43253760)
#define B_POS    ((size_t)42729472)
#define B_LSEP   ((size_t)42754560)
#define B_LGR    ((size_t)42930176)
#define B_FLAG   ((size_t)42930688)

extern "C" void kernel_launch(void* const* d_in, const int* in_sizes, int n_in,
                              void* d_out, int out_size, void* d_ws, size_t ws_size,
                              hipStream_t stream) {
    (void)in_sizes; (void)n_in; (void)out_size;
    const void* feat_q = d_in[0];
    const void* feat_k = d_in[1];
    const void* Wg1 = d_in[2];  const void* bg1 = d_in[3];
    const void* Wg2 = d_in[4];  const void* bg2 = d_in[5];
    const void* Wd1 = d_in[6];  const void* bd1 = d_in[7];
    const void* Wd2 = d_in[8];  const void* bd2 = d_in[9];
    const void* mWg1 = d_in[10]; const void* mbg1 = d_in[11];
    const void* mWg2 = d_in[12]; const void* mbg2 = d_in[13];
    const void* mWd1 = d_in[14]; const void* mbd1 = d_in[15];
    const void* mWd2 = d_in[16]; const void* mbd2 = d_in[17];
    char* ws = (char*)d_ws;

    if (ws_size >= A_NEED) {
        // =================== BIG PATH ===================
        unsigned short* FQ    = (unsigned short*)(ws + A_FQ);
        unsigned short* FK    = (unsigned short*)(ws + A_FK);
        unsigned short* WD1T  = (unsigned short*)(ws + A_WD1T);
        unsigned short* MWD1T = (unsigned short*)(ws + A_MWD1T);
        unsigned short* WG1T  = (unsigned short*)(ws + A_WG1T);
        unsigned short* MWG1T = (unsigned short*)(ws + A_MWG1T);
        unsigned short* W2dq  = (unsigned short*)(ws + A_W2DQ);
        unsigned short* W2dk  = (unsigned short*)(ws + A_W2DK);
        unsigned short* W2gq  = (unsigned short*)(ws + A_W2GQ);
        unsigned short* W2gk  = (unsigned short*)(ws + A_W2GK);
        float* rawdq = (float*)(ws + A_RAWDQ);
        float* rawdk = (float*)(ws + A_RAWDK);
        float* rawgq = (float*)(ws + A_RAWGQ);
        float* rawgk = (float*)(ws + A_RAWGK);
        unsigned short* gq = (unsigned short*)(ws + A_GQ);
        unsigned short* gk = (unsigned short*)(ws + A_GK);
        unsigned short* qd = (unsigned short*)(ws + A_QD);
        unsigned short* kd = (unsigned short*)(ws + A_KD);
        unsigned short* mt = (unsigned short*)(ws + A_MT);
        float* pos  = (float*)(ws + A_POS);
        float* lsep = (float*)(ws + A_RAWDQ);   // rawdq region is dead after simmatch
        float* lgr  = (float*)(ws + A_LGR);
        int*   flag = (int*)(ws + A_FLAG);

        detect_kernel<<<1, 64, 0, stream>>>((const unsigned short*)feat_q, flag);
        prep_kernel<<<6464, 256, 0, stream>>>(
            feat_q, feat_k, FQ, FK, gq, gk,
            Wd1, mWd1, Wg1, mWg1, WD1T, MWD1T, WG1T, MWG1T,
            Wd2, mWd2, Wg2, mWg2, W2dq, W2dk, W2gq, W2gk,
            rawdq, flag);
        mlp_mega_kernel<<<dim3(16, 50, 2), 256, 0, stream>>>(
            FQ, FK, gq, gk, WD1T, MWD1T, WG1T, MWG1T,
            W2dq, W2dk, W2gq, W2gk, bd1, mbd1, bg1, mbg1,
            rawdq, rawdk, rawgq, rawgk, flag);
        simmatch_kernel<<<dim3(128, 2), 256, 0, stream>>>(rawdq, rawdk, bd2, mbd2, qd, kd, mt, pos, flag);
        lse_kernel<<<dim3(49, NZSPLIT), 256, 0, stream>>>(qd, mt, lsep);
        lg_kernel<<<16, 128, 0, stream>>>(rawgq, rawgk, bg2, mbg2, lgr, flag);
        final_kernel<<<1, 256, 0, stream>>>(lsep, pos, lgr, (unsigned int*)d_out);
    } else {
        // =================== SMALL PATH ===================
        unsigned short* slotA = (unsigned short*)(ws + B_SLOTA);
        unsigned short* slotB = (unsigned short*)(ws + B_SLOTB);
        unsigned short* W2dq = (unsigned short*)(ws + B_W2DQ);
        unsigned short* W2dk = (unsigned short*)(ws + B_W2DK);
        unsigned short* W2gq = (unsigned short*)(ws + B_W2GQ);
        unsigned short* W2gk = (unsigned short*)(ws + B_W2GK);
        float* rawdq = (float*)(ws + B_RAWDQ);
        float* rawdk = (float*)(ws + B_RAWDK);
        float* rawgq = (float*)(ws + B_RAWGQ);
        float* rawgk = (float*)(ws + B_RAWGK);
        unsigned short* gq = (unsigned short*)(ws + B_GQ);
        unsigned short* gk = (unsigned short*)(ws + B_GK);
        unsigned short* qd = (unsigned short*)(ws + B_QD);
        unsigned short* kd = (unsigned short*)(ws + B_KD);
        unsigned short* mt = (unsigned short*)(ws + B_MT);
        float* pos  = (float*)(ws + B_POS);
        float* lsep = (float*)(ws + B_RAWDQ);   // rawdq region dead after simmatch
        float* lgr  = (float*)(ws + B_LGR);
        int*   flag = (int*)(ws + B_FLAG);

        detect_kernel<<<1, 64, 0, stream>>>((const unsigned short*)feat_q, flag);
        pool_kernel<<<dim3(8, 128, 2), 256, 0, stream>>>(feat_q, feat_k, gq, gk, flag);
        transpose2v_kernel<<<dim3(32, 32, 2), 256, 0, stream>>>(Wg1, mWg1, slotA, slotB, 2048, 2048, flag);
        transpose4v_kernel<<<dim3(2, 32, 4), 256, 0, stream>>>(
            Wd2, mWd2, Wg2, mWg2, W2dq, W2dk, W2gq, W2gk, 2048, 128, flag);
        zero_kernel<<<1600, 256, 0, stream>>>(rawdq, 409600);
        mlp_kernel<<<dim3(16, 1, 2), 256, 0, stream>>>(
            gq, gk, slotA, slotB, W2gq, W2gk, bg1, mbg1, rawgq, rawgk, flag);
        transpose2v_kernel<<<dim3(32, 32, 1), 256, 0, stream>>>(Wd1, Wd1, slotA, slotA, 2048, 2048, flag);
        convert_kernel<<<6272, 256, 0, stream>>>(feat_q, slotB, flag);
        mlp_kernel<<<dim3(16, 49, 1), 256, 0, stream>>>(
            slotB, slotB, slotA, slotA, W2dq, W2dq, bd1, bd1, rawdq, rawdq, flag);
        transpose2v_kernel<<<dim3(32, 32, 1), 256, 0, stream>>>(mWd1, mWd1, slotA, slotA, 2048, 2048, flag);
        convert_kernel<<<6272, 256, 0, stream>>>(feat_k, slotB, flag);
        mlp_kernel<<<dim3(16, 49, 1), 256, 0, stream>>>(
            slotB, slotB, slotA, slotA, W2dk, W2dk, mbd1, mbd1, rawdk, rawdk, flag);
        simmatch_kernel<<<dim3(128, 2), 256, 0, stream>>>(rawdq, rawdk, bd2, mbd2, qd, kd, mt, pos, flag);
        lse_kernel<<<dim3(49, NZSPLIT), 256, 0, stream>>>(qd, mt, lsep);
        lg_kernel<<<16, 128, 0, stream>>>(rawgq, rawgk, bg2, mbg2, lgr, flag);
        final_kernel<<<1, 256, 0, stream>>>(lsep, pos, lgr, (unsigned int*)d_out);
    }
}